// Round 2
// baseline (5252.216 us; speedup 1.0000x reference)
//
#include <hip/hip_runtime.h>
#include <hip/hip_bf16.h>

#define B_   2
#define S_   2048
#define D_   1024
#define H_   16
#define HD_  64
#define HID_ 2816

typedef unsigned short u16;
typedef unsigned int   u32;

static __device__ __forceinline__ float bf2f(u16 u){ return __uint_as_float(((u32)u)<<16); }
static __device__ __forceinline__ u16 f2bf(float f){
  u32 u = __float_as_uint(f);
  u32 r = (u + 0x7FFFu + ((u>>16)&1u)) >> 16;   // round-to-nearest-even
  return (u16)r;
}

// fixed-dtype helpers (workspace tensors are always bf16 / fp32 as typed)
static __device__ __forceinline__ void ld4(const u16* p, float* v){
  ushort4 t = *reinterpret_cast<const ushort4*>(p);
  v[0]=bf2f(t.x); v[1]=bf2f(t.y); v[2]=bf2f(t.z); v[3]=bf2f(t.w);
}
static __device__ __forceinline__ void ld4(const float* p, float* v){
  float4 t = *reinterpret_cast<const float4*>(p);
  v[0]=t.x; v[1]=t.y; v[2]=t.z; v[3]=t.w;
}
static __device__ __forceinline__ void st4(u16* p, const float* v){
  ushort4 t; t.x=f2bf(v[0]); t.y=f2bf(v[1]); t.z=f2bf(v[2]); t.w=f2bf(v[3]);
  *reinterpret_cast<ushort4*>(p)=t;
}

// dtype-dispatched helpers for harness inputs/output (flag: 1 = fp32, 0 = bf16)
static __device__ __forceinline__ float ld1g(const void* p, size_t i, bool f32){
  return f32 ? ((const float*)p)[i] : bf2f(((const u16*)p)[i]);
}
static __device__ __forceinline__ void ld4g(const void* p, size_t i, float* v, bool f32){
  if(f32){
    float4 t = *reinterpret_cast<const float4*>((const float*)p + i);
    v[0]=t.x; v[1]=t.y; v[2]=t.z; v[3]=t.w;
  }else{
    ushort4 t = *reinterpret_cast<const ushort4*>((const u16*)p + i);
    v[0]=bf2f(t.x); v[1]=bf2f(t.y); v[2]=bf2f(t.z); v[3]=bf2f(t.w);
  }
}
static __device__ __forceinline__ void st4g(void* p, size_t i, const float* v, bool f32){
  if(f32){
    float4 t; t.x=v[0]; t.y=v[1]; t.z=v[2]; t.w=v[3];
    *reinterpret_cast<float4*>((float*)p + i) = t;
  }else{
    st4((u16*)p + i, v);
  }
}

// ---- dtype probe: freqs_cos[0]==1.0f. fp32 -> first u16 is 0x0000; bf16 -> 0x3F80.
__global__ void k_probe(const u16* fc_raw, int* flag){
  if(threadIdx.x==0 && blockIdx.x==0) *flag = (fc_raw[0]==0) ? 1 : 0;
}

// block reduction over 256 threads (4 waves of 64)
static __device__ __forceinline__ float blk_sum(float v, float* red){
  #pragma unroll
  for(int o=32;o;o>>=1) v += __shfl_xor(v,o,64);
  int lane = threadIdx.x & 63, w = threadIdx.x >> 6;
  if(lane==0) red[w]=v;
  __syncthreads();
  float t = red[0]+red[1]+red[2]+red[3];
  __syncthreads();
  return t;
}

// ---- adaLN modulation vector: m[b][n] = silu(a[b]) . ada_w[:,n] + ada_b[n]
__global__ __launch_bounds__(256) void k_adaln(const void* a, const void* W, const void* bias,
                                               float* m, const int* flag){
  bool f32 = flag[0] != 0;
  __shared__ float sl[2][1024];
  for(int i=threadIdx.x;i<2048;i+=256){
    int bb=i>>10, d=i&1023;
    float x = ld1g(a, bb*D_+d, f32);
    sl[bb][d]=x/(1.f+__expf(-x));
  }
  __syncthreads();
  int n = blockIdx.x*256 + threadIdx.x;
  float a0 = ld1g(bias, n, f32), a1 = a0;
  for(int kk=0;kk<1024;kk++){
    float w = ld1g(W, (size_t)kk*6144+n, f32);
    a0 += sl[0][kk]*w; a1 += sl[1][kk]*w;
  }
  m[n] = a0; m[6144+n] = a1;
}

// ---- h = rmsnorm(x, nw) * (1+scale) + shift  (one block per row)
// force_f32x: 1 -> x is fp32 workspace; 0 -> x is harness input (use flag)
__global__ __launch_bounds__(256) void k_rms_mod(const void* x, const void* nw, const float* m,
                                                 u16* h, int shift_off, int scale_off,
                                                 const int* flag, int force_f32x){
  bool f32in = flag[0] != 0;
  bool f32x  = force_f32x ? true : f32in;
  __shared__ float red[4];
  int row = blockIdx.x; int b = row >> 11;
  int d0 = threadIdx.x*4;
  float v[4]; ld4g(x, (size_t)row*D_ + d0, v, f32x);
  float ss = v[0]*v[0]+v[1]*v[1]+v[2]*v[2]+v[3]*v[3];
  float tot = blk_sum(ss, red);
  float r = rsqrtf(tot*(1.f/D_) + 1e-5f);
  const float* mb = m + b*6144;
  float wn[4]; ld4g(nw, d0, wn, f32in);
  float o[4];
  #pragma unroll
  for(int j=0;j<4;j++){
    int d = d0+j;
    o[j] = v[j]*r*wn[j]*(1.f+mb[scale_off+d]) + mb[shift_off+d];
  }
  st4(h + (size_t)row*D_ + d0, o);
}

// ---- in-place layernorm (over full DIM) + RoPE per head; t is ws bf16
__global__ __launch_bounds__(256) void k_ln_rope(u16* t, const void* w, const void* bb,
                                                 const void* fc, const void* fs, const int* flag){
  bool f32 = flag[0] != 0;
  __shared__ float red[4];
  int row = blockIdx.x; int s = row & (S_-1);
  int d0 = threadIdx.x*4;
  float v[4]; ld4(t + (size_t)row*D_ + d0, v);
  float sm = v[0]+v[1]+v[2]+v[3];
  float sq = v[0]*v[0]+v[1]*v[1]+v[2]*v[2]+v[3]*v[3];
  float tsm = blk_sum(sm, red);
  float tsq = blk_sum(sq, red);
  float mu  = tsm*(1.f/D_);
  float var = tsq*(1.f/D_) - mu*mu;
  float rs  = rsqrtf(var + 1e-5f);
  float wv[4], bv[4]; ld4g(w, d0, wv, f32); ld4g(bb, d0, bv, f32);
  float y[4];
  #pragma unroll
  for(int j=0;j<4;j++) y[j] = (v[j]-mu)*rs*wv[j] + bv[j];
  int pos = d0 & 63; int i0 = pos>>1;
  float c0 = ld1g(fc, s*32+i0,   f32), s0 = ld1g(fs, s*32+i0,   f32);
  float c1 = ld1g(fc, s*32+i0+1, f32), s1 = ld1g(fs, s*32+i0+1, f32);
  float o[4];
  o[0] = y[0]*c0 - y[1]*s0;
  o[1] = y[0]*s0 + y[1]*c0;
  o[2] = y[2]*c1 - y[3]*s1;
  o[3] = y[2]*s1 + y[3]*c1;
  st4(t + (size_t)row*D_ + d0, o);
}

// ---- GEMM, fp32 accumulate: C(M,N) = A(M,K) @ B(K,N); A,C ws bf16; B harness input
__global__ __launch_bounds__(256) void k_gemm(const u16* A, const void* Bm, u16* C,
                                              int M, int N, int K, const int* flag){
  bool f32 = flag[0] != 0;
  __shared__ float As[16][64];
  __shared__ float Bs[16][64];
  int tid = threadIdx.x;
  int row0 = blockIdx.y*64, col0 = blockIdx.x*64;
  int am = tid>>2, akg = (tid&3)*4;
  int bk = tid>>4, bng = (tid&15)*4;
  int ty = tid>>4, tx = tid&15;
  float acc[4][4] = {};
  for(int k0=0;k0<K;k0+=16){
    if(k0) __syncthreads();
    float av[4]; ld4(A + (size_t)(row0+am)*K + k0+akg, av);
    float bv[4]; ld4g(Bm, (size_t)(k0+bk)*N + col0+bng, bv, f32);
    #pragma unroll
    for(int c=0;c<4;c++){ As[akg+c][am]=av[c]; Bs[bk][bng+c]=bv[c]; }
    __syncthreads();
    #pragma unroll
    for(int kk=0;kk<16;kk++){
      float a4[4], b4[4];
      *reinterpret_cast<float4*>(a4) = *reinterpret_cast<const float4*>(&As[kk][ty*4]);
      *reinterpret_cast<float4*>(b4) = *reinterpret_cast<const float4*>(&Bs[kk][tx*4]);
      #pragma unroll
      for(int i=0;i<4;i++)
        #pragma unroll
        for(int j=0;j<4;j++)
          acc[i][j] += a4[i]*b4[j];
    }
  }
  #pragma unroll
  for(int i=0;i<4;i++)
    st4(C + (size_t)(row0+ty*4+i)*N + col0 + tx*4, acc[i]);
}

// ---- attention: one wave per query row, online softmax (all ws bf16)
__global__ __launch_bounds__(256) void k_attn(const u16* q, const u16* k, const u16* v, u16* o){
  __shared__ float qs[4][64];
  int lane = threadIdx.x & 63, wid = threadIdx.x >> 6;
  int gr = blockIdx.x*4 + wid;
  int s  = gr & (S_-1);
  int bh = gr >> 11;
  int h  = bh & (H_-1);
  int b  = bh >> 4;
  const u16* qrow = q + ((size_t)(b*S_+s)*D_ + h*HD_);
  qs[wid][lane] = bf2f(qrow[lane]);
  __syncthreads();
  const u16* kb = k + ((size_t)b*S_*D_ + h*HD_);
  const u16* vb = v + ((size_t)b*S_*D_ + h*HD_);
  float mx = -1e30f, l = 0.f, acc = 0.f;
  for(int t0=0;t0<S_;t0+=64){
    const u16* kr = kb + (size_t)(t0+lane)*D_;
    float sc = 0.f;
    #pragma unroll
    for(int i=0;i<64;i+=8){
      uint4 kk = *reinterpret_cast<const uint4*>(kr+i);
      sc += qs[wid][i+0]*bf2f((u16)(kk.x&0xFFFF)) + qs[wid][i+1]*bf2f((u16)(kk.x>>16))
          + qs[wid][i+2]*bf2f((u16)(kk.y&0xFFFF)) + qs[wid][i+3]*bf2f((u16)(kk.y>>16))
          + qs[wid][i+4]*bf2f((u16)(kk.z&0xFFFF)) + qs[wid][i+5]*bf2f((u16)(kk.z>>16))
          + qs[wid][i+6]*bf2f((u16)(kk.w&0xFFFF)) + qs[wid][i+7]*bf2f((u16)(kk.w>>16));
    }
    sc *= 0.125f;
    float cm = sc;
    #pragma unroll
    for(int off=32;off;off>>=1) cm = fmaxf(cm, __shfl_xor(cm,off,64));
    float mn = fmaxf(mx, cm);
    float alpha = __expf(mx - mn);
    float p  = __expf(sc - mn);
    float ps = p;
    #pragma unroll
    for(int off=32;off;off>>=1) ps += __shfl_xor(ps,off,64);
    l = l*alpha + ps;
    mx = mn;
    acc *= alpha;
    const u16* vr = vb + (size_t)t0*D_;
    #pragma unroll 8
    for(int t=0;t<64;t++){
      float pt = __shfl(p, t, 64);
      acc += pt * bf2f(vr[(size_t)t*D_ + lane]);
    }
  }
  acc /= l;
  o[((size_t)(b*S_+s)*H_ + h)*HD_ + lane] = f2bf(acc);
}

// ---- x2 = x + gate*y  (x harness input, y ws bf16 -> fp32 ws)
__global__ __launch_bounds__(256) void k_resid_f(const void* x, const u16* y, const float* m,
                                                 int gate_off, float* o, const int* flag){
  bool f32 = flag[0] != 0;
  size_t i4 = ((size_t)blockIdx.x*256 + threadIdx.x)*4;
  int d = (int)(i4 & (D_-1));
  int b = (int)(i4 >> 21);
  float xv[4], yv[4];
  ld4g(x, i4, xv, f32); ld4(y+i4, yv);
  const float* g = m + b*6144 + gate_off + d;
  float4 r; r.x=xv[0]+g[0]*yv[0]; r.y=xv[1]+g[1]*yv[1]; r.z=xv[2]+g[2]*yv[2]; r.w=xv[3]+g[3]*yv[3];
  *reinterpret_cast<float4*>(o+i4) = r;
}

// ---- out = x2 + gate*y  (fp32 ws, bf16 ws -> harness output dtype)
__global__ __launch_bounds__(256) void k_resid_b(const float* x, const u16* y, const float* m,
                                                 int gate_off, void* o, const int* flag){
  bool f32 = flag[0] != 0;
  size_t i4 = ((size_t)blockIdx.x*256 + threadIdx.x)*4;
  int d = (int)(i4 & (D_-1));
  int b = (int)(i4 >> 21);
  float xv[4], yv[4];
  ld4(x+i4, xv); ld4(y+i4, yv);
  const float* g = m + b*6144 + gate_off + d;
  float r[4];
  #pragma unroll
  for(int j=0;j<4;j++) r[j] = xv[j] + g[j]*yv[j];
  st4g(o, i4, r, f32);
}

// ---- g = silu(h1)*h3 (ws bf16)
__global__ __launch_bounds__(256) void k_silu_mul(const u16* h1, const u16* h3, u16* g){
  size_t i4 = ((size_t)blockIdx.x*256 + threadIdx.x)*4;
  float a[4], c[4];
  ld4(h1+i4, a); ld4(h3+i4, c);
  float r[4];
  #pragma unroll
  for(int j=0;j<4;j++){ float sv = a[j]/(1.f+__expf(-a[j])); r[j] = sv*c[j]; }
  st4(g+i4, r);
}

extern "C" void kernel_launch(void* const* d_in, const int* in_sizes, int n_in,
                              void* d_out, int out_size, void* d_ws, size_t ws_size,
                              hipStream_t stream){
  const void* x   = d_in[0];
  const void* ada = d_in[1];
  const void* fc  = d_in[2];
  const void* fs  = d_in[3];
  const void* wq  = d_in[4];
  const void* wk  = d_in[5];
  const void* wv  = d_in[6];
  const void* wo  = d_in[7];
  const void* qnw = d_in[8];
  const void* qnb = d_in[9];
  const void* knw = d_in[10];
  const void* knb = d_in[11];
  const void* anw = d_in[12];
  const void* fnw = d_in[13];
  const void* aw  = d_in[14];
  const void* ab  = d_in[15];
  const void* w1  = d_in[16];
  const void* w2  = d_in[17];
  const void* w3  = d_in[18];
  char* ws = (char*)d_ws;
  const size_t MB = 1u<<20;

  int*   flag = (int*)ws;                 // 4 B
  float* m    = (float*)(ws + 4096);      // 48 KB
  u16* hbuf   = (u16*)(ws + 1*MB);        // region A: h -> attn -> h2 (8MB)
  u16* xq     = (u16*)(ws + 9*MB);        // region B: xq -> proj -> ffn (8MB)
  u16* xk     = (u16*)(ws + 17*MB);       // region C (8MB)
  u16* xv     = (u16*)(ws + 25*MB);       // region D (8MB)
  u16* h1     = (u16*)(ws + 33*MB);       // region E: h1/g (22MB)
  u16* h3     = (u16*)(ws + 56*MB);       // region F (22MB)
  float* x2   = (float*)(ws + 79*MB);     // region G: fp32 residual (16MB)
  u16* attn = hbuf;
  u16* h2   = hbuf;
  u16* proj = xq;
  u16* ffn  = xq;

  dim3 blk(256);
  dim3 g1(1024/64, 4096/64);
  dim3 g2(2816/64, 4096/64);

  k_probe<<<dim3(1), dim3(64), 0, stream>>>((const u16*)fc, flag);
  k_adaln<<<dim3(24), blk, 0, stream>>>(ada, aw, ab, m, flag);
  k_rms_mod<<<dim3(B_*S_), blk, 0, stream>>>(x, anw, m, hbuf, 0, 1024, flag, 0);
  k_gemm<<<g1, blk, 0, stream>>>(hbuf, wq, xq, 4096, 1024, 1024, flag);
  k_gemm<<<g1, blk, 0, stream>>>(hbuf, wk, xk, 4096, 1024, 1024, flag);
  k_gemm<<<g1, blk, 0, stream>>>(hbuf, wv, xv, 4096, 1024, 1024, flag);
  k_ln_rope<<<dim3(B_*S_), blk, 0, stream>>>(xq, qnw, qnb, fc, fs, flag);
  k_ln_rope<<<dim3(B_*S_), blk, 0, stream>>>(xk, knw, knb, fc, fs, flag);
  k_attn<<<dim3(B_*H_*S_/4), blk, 0, stream>>>(xq, xk, xv, attn);
  k_gemm<<<g1, blk, 0, stream>>>(attn, wo, proj, 4096, 1024, 1024, flag);
  k_resid_f<<<dim3(4096), blk, 0, stream>>>(x, proj, m, 2048, x2, flag);
  k_rms_mod<<<dim3(B_*S_), blk, 0, stream>>>(x2, fnw, m, h2, 3072, 4096, flag, 1);
  k_gemm<<<g2, blk, 0, stream>>>(h2, w1, h1, 4096, 2816, 1024, flag);
  k_gemm<<<g2, blk, 0, stream>>>(h2, w3, h3, 4096, 2816, 1024, flag);
  k_silu_mul<<<dim3(11264), blk, 0, stream>>>(h1, h3, h1);
  k_gemm<<<g1, blk, 0, stream>>>(h1, w2, ffn, 4096, 1024, 2816, flag);
  k_resid_b<<<dim3(4096), blk, 0, stream>>>(x2, ffn, m, 5120, out_size ? d_out : d_out, flag);
}

// Round 3
// 1864.835 us; speedup vs baseline: 2.8165x; 2.8165x over previous
//
#include <hip/hip_runtime.h>
#include <hip/hip_bf16.h>

#define B_   2
#define S_   2048
#define D_   1024
#define H_   16
#define HD_  64
#define HID_ 2816

typedef unsigned short u16;
typedef unsigned int   u32;
typedef __attribute__((ext_vector_type(8))) short short8;
typedef __attribute__((ext_vector_type(4))) float f32x4;

static __device__ __forceinline__ float bf2f(u16 u){ return __uint_as_float(((u32)u)<<16); }
static __device__ __forceinline__ u16 f2bf(float f){
  u32 u = __float_as_uint(f);
  u32 r = (u + 0x7FFFu + ((u>>16)&1u)) >> 16;   // round-to-nearest-even
  return (u16)r;
}

static __device__ __forceinline__ void ld4(const u16* p, float* v){
  ushort4 t = *reinterpret_cast<const ushort4*>(p);
  v[0]=bf2f(t.x); v[1]=bf2f(t.y); v[2]=bf2f(t.z); v[3]=bf2f(t.w);
}
static __device__ __forceinline__ void ld4(const float* p, float* v){
  float4 t = *reinterpret_cast<const float4*>(p);
  v[0]=t.x; v[1]=t.y; v[2]=t.z; v[3]=t.w;
}
static __device__ __forceinline__ void st4(u16* p, const float* v){
  ushort4 t; t.x=f2bf(v[0]); t.y=f2bf(v[1]); t.z=f2bf(v[2]); t.w=f2bf(v[3]);
  *reinterpret_cast<ushort4*>(p)=t;
}

// dtype-dispatched helpers for harness inputs/output (flag: 1 = fp32, 0 = bf16)
static __device__ __forceinline__ float ld1g(const void* p, size_t i, bool f32){
  return f32 ? ((const float*)p)[i] : bf2f(((const u16*)p)[i]);
}
static __device__ __forceinline__ void ld4g(const void* p, size_t i, float* v, bool f32){
  if(f32){
    float4 t = *reinterpret_cast<const float4*>((const float*)p + i);
    v[0]=t.x; v[1]=t.y; v[2]=t.z; v[3]=t.w;
  }else{
    ushort4 t = *reinterpret_cast<const ushort4*>((const u16*)p + i);
    v[0]=bf2f(t.x); v[1]=bf2f(t.y); v[2]=bf2f(t.z); v[3]=bf2f(t.w);
  }
}
static __device__ __forceinline__ void st4g(void* p, size_t i, const float* v, bool f32){
  if(f32){
    float4 t; t.x=v[0]; t.y=v[1]; t.z=v[2]; t.w=v[3];
    *reinterpret_cast<float4*>((float*)p + i) = t;
  }else{
    st4((u16*)p + i, v);
  }
}

// ---- dtype probe: freqs_cos[0]==1.0f. fp32 -> first u16 is 0x0000; bf16 -> 0x3F80.
__global__ void k_probe(const u16* fc_raw, int* flag){
  if(threadIdx.x==0 && blockIdx.x==0) *flag = (fc_raw[0]==0) ? 1 : 0;
}

static __device__ __forceinline__ float blk_sum(float v, float* red){
  #pragma unroll
  for(int o=32;o;o>>=1) v += __shfl_xor(v,o,64);
  int lane = threadIdx.x & 63, w = threadIdx.x >> 6;
  if(lane==0) red[w]=v;
  __syncthreads();
  float t = red[0]+red[1]+red[2]+red[3];
  __syncthreads();
  return t;
}

__global__ __launch_bounds__(256) void k_adaln(const void* a, const void* W, const void* bias,
                                               float* m, const int* flag){
  bool f32 = flag[0] != 0;
  __shared__ float sl[2][1024];
  for(int i=threadIdx.x;i<2048;i+=256){
    int bb=i>>10, d=i&1023;
    float x = ld1g(a, bb*D_+d, f32);
    sl[bb][d]=x/(1.f+__expf(-x));
  }
  __syncthreads();
  int n = blockIdx.x*256 + threadIdx.x;
  float a0 = ld1g(bias, n, f32), a1 = a0;
  for(int kk=0;kk<1024;kk++){
    float w = ld1g(W, (size_t)kk*6144+n, f32);
    a0 += sl[0][kk]*w; a1 += sl[1][kk]*w;
  }
  m[n] = a0; m[6144+n] = a1;
}

__global__ __launch_bounds__(256) void k_rms_mod(const void* x, const void* nw, const float* m,
                                                 u16* h, int shift_off, int scale_off,
                                                 const int* flag, int force_f32x){
  bool f32in = flag[0] != 0;
  bool f32x  = force_f32x ? true : f32in;
  __shared__ float red[4];
  int row = blockIdx.x; int b = row >> 11;
  int d0 = threadIdx.x*4;
  float v[4]; ld4g(x, (size_t)row*D_ + d0, v, f32x);
  float ss = v[0]*v[0]+v[1]*v[1]+v[2]*v[2]+v[3]*v[3];
  float tot = blk_sum(ss, red);
  float r = rsqrtf(tot*(1.f/D_) + 1e-5f);
  const float* mb = m + b*6144;
  float wn[4]; ld4g(nw, d0, wn, f32in);
  float o[4];
  #pragma unroll
  for(int j=0;j<4;j++){
    int d = d0+j;
    o[j] = v[j]*r*wn[j]*(1.f+mb[scale_off+d]) + mb[shift_off+d];
  }
  st4(h + (size_t)row*D_ + d0, o);
}

__global__ __launch_bounds__(256) void k_ln_rope(u16* t, const void* w, const void* bb,
                                                 const void* fc, const void* fs, const int* flag){
  bool f32 = flag[0] != 0;
  __shared__ float red[4];
  int row = blockIdx.x; int s = row & (S_-1);
  int d0 = threadIdx.x*4;
  float v[4]; ld4(t + (size_t)row*D_ + d0, v);
  float sm = v[0]+v[1]+v[2]+v[3];
  float sq = v[0]*v[0]+v[1]*v[1]+v[2]*v[2]+v[3]*v[3];
  float tsm = blk_sum(sm, red);
  float tsq = blk_sum(sq, red);
  float mu  = tsm*(1.f/D_);
  float var = tsq*(1.f/D_) - mu*mu;
  float rs  = rsqrtf(var + 1e-5f);
  float wv[4], bv[4]; ld4g(w, d0, wv, f32); ld4g(bb, d0, bv, f32);
  float y[4];
  #pragma unroll
  for(int j=0;j<4;j++) y[j] = (v[j]-mu)*rs*wv[j] + bv[j];
  int pos = d0 & 63; int i0 = pos>>1;
  float c0 = ld1g(fc, s*32+i0,   f32), s0 = ld1g(fs, s*32+i0,   f32);
  float c1 = ld1g(fc, s*32+i0+1, f32), s1 = ld1g(fs, s*32+i0+1, f32);
  float o[4];
  o[0] = y[0]*c0 - y[1]*s0;
  o[1] = y[0]*s0 + y[1]*c0;
  o[2] = y[2]*c1 - y[3]*s1;
  o[3] = y[2]*s1 + y[3]*c1;
  st4(t + (size_t)row*D_ + d0, o);
}

// ---- GEMM, fp32 accumulate: C(M,N) = A(M,K) @ B(K,N); A,C ws bf16; B harness input
__global__ __launch_bounds__(256) void k_gemm(const u16* A, const void* Bm, u16* C,
                                              int M, int N, int K, const int* flag){
  bool f32 = flag[0] != 0;
  __shared__ float As[16][64];
  __shared__ float Bs[16][64];
  int tid = threadIdx.x;
  int row0 = blockIdx.y*64, col0 = blockIdx.x*64;
  int am = tid>>2, akg = (tid&3)*4;
  int bk = tid>>4, bng = (tid&15)*4;
  int ty = tid>>4, tx = tid&15;
  float acc[4][4] = {};
  for(int k0=0;k0<K;k0+=16){
    if(k0) __syncthreads();
    float av[4]; ld4(A + (size_t)(row0+am)*K + k0+akg, av);
    float bv[4]; ld4g(Bm, (size_t)(k0+bk)*N + col0+bng, bv, f32);
    #pragma unroll
    for(int c=0;c<4;c++){ As[akg+c][am]=av[c]; Bs[bk][bng+c]=bv[c]; }
    __syncthreads();
    #pragma unroll
    for(int kk=0;kk<16;kk++){
      float a4[4], b4[4];
      *reinterpret_cast<float4*>(a4) = *reinterpret_cast<const float4*>(&As[kk][ty*4]);
      *reinterpret_cast<float4*>(b4) = *reinterpret_cast<const float4*>(&Bs[kk][tx*4]);
      #pragma unroll
      for(int i=0;i<4;i++)
        #pragma unroll
        for(int j=0;j<4;j++)
          acc[i][j] += a4[i]*b4[j];
    }
  }
  #pragma unroll
  for(int i=0;i<4;i++)
    st4(C + (size_t)(row0+ty*4+i)*N + col0 + tx*4, acc[i]);
}

// ---- V transpose: vt[(b*H+h)][hd][key] <- v[(b*S+key)][h*64+hd]
__global__ __launch_bounds__(256) void k_vt(const u16* v, u16* vt){
  __shared__ u16 L[64][72];
  int tid = threadIdx.x;
  int wg = blockIdx.x;
  int kblk = wg & 31; int bh = wg >> 5; int h = bh & 15, b = bh >> 4;
  int row = tid>>2, c0 = (tid&3)*16;
  const u16* src = v + ((size_t)(b*S_ + kblk*64 + row))*D_ + h*HD_ + c0;
  *reinterpret_cast<short8*>(&L[row][c0])   = *reinterpret_cast<const short8*>(src);
  *reinterpret_cast<short8*>(&L[row][c0+8]) = *reinterpret_cast<const short8*>(src+8);
  __syncthreads();
  int hd = tid>>2, k0 = (tid&3)*16;
  u16 tmp[16];
  #pragma unroll
  for(int j=0;j<16;j++) tmp[j] = L[k0+j][hd];
  u16* dst = vt + ((size_t)bh*HD_ + hd)*S_ + kblk*64 + k0;
  *reinterpret_cast<short8*>(dst)   = *reinterpret_cast<const short8*>(tmp);
  *reinterpret_cast<short8*>(dst+8) = *reinterpret_cast<const short8*>(tmp+8);
}

// ---- MFMA flash attention. WG = 4 waves; wave owns 16 q-rows; loop 32-key chunks.
// q,k layout [b*S+s][D] (head slice at h*64); vt layout [bh][hd][key]; out [b*S+s][D].
__global__ __launch_bounds__(256) void k_attn_mfma(const u16* q, const u16* k, const u16* vt,
                                                   u16* o){
  __shared__ u16 Ks[32][72];      // [key][hd], +8 pad -> 2-way-max on b128 frag reads
  __shared__ u16 Vs[64][40];      // [hd][key], +8 pad
  __shared__ u16 Ps[4][16][40];   // per-wave P: [qrow][key], +8 pad
  int tid = threadIdx.x, lane = tid & 63, wid = tid >> 6;
  int col = lane & 15, quad = lane >> 4;
  int wg = blockIdx.x;
  int qblk = wg & 31; int bh = wg >> 5; int h = bh & 15, b = bh >> 4;

  const u16* kb  = k  + ((size_t)b*S_)*D_ + h*HD_;
  const u16* vtb = vt + ((size_t)bh*HD_)*S_;

  short8 qa0, qa1;
  {
    const u16* qp = q + ((size_t)(b*S_ + qblk*64 + wid*16 + col))*D_ + h*HD_ + quad*8;
    qa0 = *reinterpret_cast<const short8*>(qp);
    qa1 = *reinterpret_cast<const short8*>(qp + 32);
  }
  float m_i[4], l_i[4];
  f32x4 acc[4];
  #pragma unroll
  for(int r=0;r<4;r++){ m_i[r]=-1e30f; l_i[r]=0.f; }
  #pragma unroll
  for(int t=0;t<4;t++) acc[t] = (f32x4){0.f,0.f,0.f,0.f};

  int srow = tid>>3, sc8 = (tid&7)*8;   // K staging: 32 rows x 8 chunks
  int vrow = tid>>2, vc8 = (tid&3)*8;   // Vt staging: 64 rows x 4 chunks

  for(int kc=0;kc<64;kc++){
    __syncthreads();
    *reinterpret_cast<short8*>(&Ks[srow][sc8]) =
      *reinterpret_cast<const short8*>(kb + (size_t)(kc*32 + srow)*D_ + sc8);
    *reinterpret_cast<short8*>(&Vs[vrow][vc8]) =
      *reinterpret_cast<const short8*>(vtb + (size_t)vrow*S_ + kc*32 + vc8);
    __syncthreads();

    // QK^T: S[16q x 32k] as two 16-col C-frags
    f32x4 s0 = (f32x4){0.f,0.f,0.f,0.f}, s1 = s0;
    {
      short8 kb0 = *reinterpret_cast<const short8*>(&Ks[col][quad*8]);
      short8 kb1 = *reinterpret_cast<const short8*>(&Ks[col][quad*8+32]);
      short8 kb2 = *reinterpret_cast<const short8*>(&Ks[16+col][quad*8]);
      short8 kb3 = *reinterpret_cast<const short8*>(&Ks[16+col][quad*8+32]);
      s0 = __builtin_amdgcn_mfma_f32_16x16x32_bf16(qa0, kb0, s0, 0,0,0);
      s0 = __builtin_amdgcn_mfma_f32_16x16x32_bf16(qa1, kb1, s0, 0,0,0);
      s1 = __builtin_amdgcn_mfma_f32_16x16x32_bf16(qa0, kb2, s1, 0,0,0);
      s1 = __builtin_amdgcn_mfma_f32_16x16x32_bf16(qa1, kb3, s1, 0,0,0);
    }
    // online softmax per q-row (row = quad*4+r, held by the 16 lanes of this quad)
    #pragma unroll
    for(int r=0;r<4;r++){
      float a = s0[r]*0.125f, c = s1[r]*0.125f;
      float cm = fmaxf(a, c);
      cm = fmaxf(cm, __shfl_xor(cm,1,64));
      cm = fmaxf(cm, __shfl_xor(cm,2,64));
      cm = fmaxf(cm, __shfl_xor(cm,4,64));
      cm = fmaxf(cm, __shfl_xor(cm,8,64));
      float mn = fmaxf(m_i[r], cm);
      float al = __expf(m_i[r]-mn);
      float p0 = __expf(a-mn), p1 = __expf(c-mn);
      float ps = p0+p1;
      ps += __shfl_xor(ps,1,64);
      ps += __shfl_xor(ps,2,64);
      ps += __shfl_xor(ps,4,64);
      ps += __shfl_xor(ps,8,64);
      l_i[r] = l_i[r]*al + ps;
      m_i[r] = mn;
      #pragma unroll
      for(int t=0;t<4;t++) acc[t][r] *= al;
      Ps[wid][quad*4+r][col]    = f2bf(p0);
      Ps[wid][quad*4+r][16+col] = f2bf(p1);
    }
    asm volatile("s_waitcnt lgkmcnt(0)" ::: "memory");
    // P C-layout -> A-layout round trip, then PV
    short8 pa = *reinterpret_cast<const short8*>(&Ps[wid][col][quad*8]);
    #pragma unroll
    for(int t=0;t<4;t++){
      short8 vb = *reinterpret_cast<const short8*>(&Vs[t*16+col][quad*8]);
      acc[t] = __builtin_amdgcn_mfma_f32_16x16x32_bf16(pa, vb, acc[t], 0,0,0);
    }
  }
  int qrow = b*S_ + qblk*64 + wid*16 + quad*4;
  #pragma unroll
  for(int r=0;r<4;r++){
    float inv = 1.f/l_i[r];
    #pragma unroll
    for(int t=0;t<4;t++)
      o[(size_t)(qrow+r)*D_ + h*HD_ + t*16 + col] = f2bf(acc[t][r]*inv);
  }
}

__global__ __launch_bounds__(256) void k_resid_f(const void* x, const u16* y, const float* m,
                                                 int gate_off, float* o, const int* flag){
  bool f32 = flag[0] != 0;
  size_t i4 = ((size_t)blockIdx.x*256 + threadIdx.x)*4;
  int d = (int)(i4 & (D_-1));
  int b = (int)(i4 >> 21);
  float xv[4], yv[4];
  ld4g(x, i4, xv, f32); ld4(y+i4, yv);
  const float* g = m + b*6144 + gate_off + d;
  float4 r; r.x=xv[0]+g[0]*yv[0]; r.y=xv[1]+g[1]*yv[1]; r.z=xv[2]+g[2]*yv[2]; r.w=xv[3]+g[3]*yv[3];
  *reinterpret_cast<float4*>(o+i4) = r;
}

__global__ __launch_bounds__(256) void k_resid_b(const float* x, const u16* y, const float* m,
                                                 int gate_off, void* o, const int* flag){
  bool f32 = flag[0] != 0;
  size_t i4 = ((size_t)blockIdx.x*256 + threadIdx.x)*4;
  int d = (int)(i4 & (D_-1));
  int b = (int)(i4 >> 21);
  float xv[4], yv[4];
  ld4(x+i4, xv); ld4(y+i4, yv);
  const float* g = m + b*6144 + gate_off + d;
  float r[4];
  #pragma unroll
  for(int j=0;j<4;j++) r[j] = xv[j] + g[j]*yv[j];
  st4g(o, i4, r, f32);
}

__global__ __launch_bounds__(256) void k_silu_mul(const u16* h1, const u16* h3, u16* g){
  size_t i4 = ((size_t)blockIdx.x*256 + threadIdx.x)*4;
  float a[4], c[4];
  ld4(h1+i4, a); ld4(h3+i4, c);
  float r[4];
  #pragma unroll
  for(int j=0;j<4;j++){ float sv = a[j]/(1.f+__expf(-a[j])); r[j] = sv*c[j]; }
  st4(g+i4, r);
}

extern "C" void kernel_launch(void* const* d_in, const int* in_sizes, int n_in,
                              void* d_out, int out_size, void* d_ws, size_t ws_size,
                              hipStream_t stream){
  const void* x   = d_in[0];
  const void* ada = d_in[1];
  const void* fc  = d_in[2];
  const void* fs  = d_in[3];
  const void* wq  = d_in[4];
  const void* wk  = d_in[5];
  const void* wv  = d_in[6];
  const void* wo  = d_in[7];
  const void* qnw = d_in[8];
  const void* qnb = d_in[9];
  const void* knw = d_in[10];
  const void* knb = d_in[11];
  const void* anw = d_in[12];
  const void* fnw = d_in[13];
  const void* aw  = d_in[14];
  const void* ab  = d_in[15];
  const void* w1  = d_in[16];
  const void* w2  = d_in[17];
  const void* w3  = d_in[18];
  char* ws = (char*)d_ws;
  const size_t MB = 1u<<20;

  int*   flag = (int*)ws;
  float* m    = (float*)(ws + 4096);
  u16* hbuf   = (u16*)(ws + 1*MB);
  u16* xq     = (u16*)(ws + 9*MB);
  u16* xk     = (u16*)(ws + 17*MB);
  u16* xv     = (u16*)(ws + 25*MB);
  u16* h1     = (u16*)(ws + 33*MB);       // h1 region (FFN) — also aliases vt (disjoint liveness)
  u16* h3     = (u16*)(ws + 56*MB);
  float* x2   = (float*)(ws + 79*MB);
  u16* vt   = h1;   // live only between k_vt and k_attn_mfma; h1 written after attention
  u16* attn = hbuf;
  u16* h2   = hbuf;
  u16* proj = xq;
  u16* ffn  = xq;

  dim3 blk(256);
  dim3 g1(1024/64, 4096/64);
  dim3 g2(2816/64, 4096/64);

  k_probe<<<dim3(1), dim3(64), 0, stream>>>((const u16*)fc, flag);
  k_adaln<<<dim3(24), blk, 0, stream>>>(ada, aw, ab, m, flag);
  k_rms_mod<<<dim3(B_*S_), blk, 0, stream>>>(x, anw, m, hbuf, 0, 1024, flag, 0);
  k_gemm<<<g1, blk, 0, stream>>>(hbuf, wq, xq, 4096, 1024, 1024, flag);
  k_gemm<<<g1, blk, 0, stream>>>(hbuf, wk, xk, 4096, 1024, 1024, flag);
  k_gemm<<<g1, blk, 0, stream>>>(hbuf, wv, xv, 4096, 1024, 1024, flag);
  k_ln_rope<<<dim3(B_*S_), blk, 0, stream>>>(xq, qnw, qnb, fc, fs, flag);
  k_ln_rope<<<dim3(B_*S_), blk, 0, stream>>>(xk, knw, knb, fc, fs, flag);
  k_vt<<<dim3(B_*H_*S_/64), blk, 0, stream>>>(xv, vt);
  k_attn_mfma<<<dim3(B_*H_*S_/64), blk, 0, stream>>>(xq, xk, vt, attn);
  k_gemm<<<g1, blk, 0, stream>>>(attn, wo, proj, 4096, 1024, 1024, flag);
  k_resid_f<<<dim3(4096), blk, 0, stream>>>(x, proj, m, 2048, x2, flag);
  k_rms_mod<<<dim3(B_*S_), blk, 0, stream>>>(x2, fnw, m, h2, 3072, 4096, flag, 1);
  k_gemm<<<g2, blk, 0, stream>>>(h2, w1, h1, 4096, 2816, 1024, flag);
  k_gemm<<<g2, blk, 0, stream>>>(h2, w3, h3, 4096, 2816, 1024, flag);
  k_silu_mul<<<dim3(11264), blk, 0, stream>>>(h1, h3, h1);
  k_gemm<<<g1, blk, 0, stream>>>(h1, w2, ffn, 4096, 1024, 2816, flag);
  k_resid_b<<<dim3(4096), blk, 0, stream>>>(x2, ffn, m, 5120, d_out, flag);
}

// Round 4
// 638.088 us; speedup vs baseline: 8.2312x; 2.9225x over previous
//
#include <hip/hip_runtime.h>
#include <hip/hip_bf16.h>

#define B_   2
#define S_   2048
#define D_   1024
#define H_   16
#define HD_  64
#define HID_ 2816

typedef unsigned short u16;
typedef unsigned int   u32;
typedef __attribute__((ext_vector_type(8))) short short8;
typedef __attribute__((ext_vector_type(4))) float f32x4;

static __device__ __forceinline__ float bf2f(u16 u){ return __uint_as_float(((u32)u)<<16); }
static __device__ __forceinline__ u16 f2bf(float f){
  u32 u = __float_as_uint(f);
  u32 r = (u + 0x7FFFu + ((u>>16)&1u)) >> 16;   // round-to-nearest-even
  return (u16)r;
}

static __device__ __forceinline__ void ld4(const u16* p, float* v){
  ushort4 t = *reinterpret_cast<const ushort4*>(p);
  v[0]=bf2f(t.x); v[1]=bf2f(t.y); v[2]=bf2f(t.z); v[3]=bf2f(t.w);
}
static __device__ __forceinline__ void ld4(const float* p, float* v){
  float4 t = *reinterpret_cast<const float4*>(p);
  v[0]=t.x; v[1]=t.y; v[2]=t.z; v[3]=t.w;
}
static __device__ __forceinline__ void st4(u16* p, const float* v){
  ushort4 t; t.x=f2bf(v[0]); t.y=f2bf(v[1]); t.z=f2bf(v[2]); t.w=f2bf(v[3]);
  *reinterpret_cast<ushort4*>(p)=t;
}

static __device__ __forceinline__ float ld1g(const void* p, size_t i, bool f32){
  return f32 ? ((const float*)p)[i] : bf2f(((const u16*)p)[i]);
}
static __device__ __forceinline__ void ld4g(const void* p, size_t i, float* v, bool f32){
  if(f32){
    float4 t = *reinterpret_cast<const float4*>((const float*)p + i);
    v[0]=t.x; v[1]=t.y; v[2]=t.z; v[3]=t.w;
  }else{
    ushort4 t = *reinterpret_cast<const ushort4*>((const u16*)p + i);
    v[0]=bf2f(t.x); v[1]=bf2f(t.y); v[2]=bf2f(t.z); v[3]=bf2f(t.w);
  }
}
static __device__ __forceinline__ void st4g(void* p, size_t i, const float* v, bool f32){
  if(f32){
    float4 t; t.x=v[0]; t.y=v[1]; t.z=v[2]; t.w=v[3];
    *reinterpret_cast<float4*>((float*)p + i) = t;
  }else{
    st4((u16*)p + i, v);
  }
}

// async global->LDS, 16B per lane; LDS dest = uniform base + lane*16
static __device__ __forceinline__ void gl2lds16(const u16* g, const u16* l){
  typedef __attribute__((address_space(3))) u16 lds_u16;
  typedef const __attribute__((address_space(1))) u16 glb_u16;
  __builtin_amdgcn_global_load_lds((glb_u16*)(uintptr_t)g,
                                   (lds_u16*)(u32)(uintptr_t)l, 16, 0, 0);
}

// ---- dtype probe: freqs_cos[0]==1.0f. fp32 -> first u16 is 0x0000; bf16 -> 0x3F80.
__global__ void k_probe(const u16* fc_raw, int* flag){
  if(threadIdx.x==0 && blockIdx.x==0) *flag = (fc_raw[0]==0) ? 1 : 0;
}

__global__ __launch_bounds__(256) void k_zero(float* p, int n){
  int i = blockIdx.x*256 + threadIdx.x;
  if(i<n) p[i] = 0.f;
}

static __device__ __forceinline__ float blk_sum(float v, float* red){
  #pragma unroll
  for(int o=32;o;o>>=1) v += __shfl_xor(v,o,64);
  int lane = threadIdx.x & 63, w = threadIdx.x >> 6;
  if(lane==0) red[w]=v;
  __syncthreads();
  float t = red[0]+red[1]+red[2]+red[3];
  __syncthreads();
  return t;
}

// ---- adaLN: m[b][n] = silu(a[b]) . ada_w[:,n] + ada_b[n]; K-split + atomicAdd (m pre-zeroed)
__global__ __launch_bounds__(256) void k_adaln(const void* a, const void* W, const void* bias,
                                               float* m, const int* flag){
  bool f32 = flag[0] != 0;
  __shared__ float sl[2][128];
  int bk = blockIdx.y;
  {
    int bb = threadIdx.x >> 7, kk = threadIdx.x & 127;
    float x = ld1g(a, bb*D_ + bk*128 + kk, f32);
    sl[bb][kk] = x/(1.f+__expf(-x));
  }
  __syncthreads();
  int n = blockIdx.x*256 + threadIdx.x;
  float p0 = 0.f, p1 = 0.f;
  for(int kk=0;kk<128;kk++){
    float w = ld1g(W, (size_t)(bk*128+kk)*6144 + n, f32);
    p0 += sl[0][kk]*w; p1 += sl[1][kk]*w;
  }
  if(bk==0){ float bv = ld1g(bias, n, f32); p0 += bv; p1 += bv; }
  atomicAdd(&m[n], p0);
  atomicAdd(&m[6144+n], p1);
}

__global__ __launch_bounds__(256) void k_rms_mod(const void* x, const void* nw, const float* m,
                                                 u16* h, int shift_off, int scale_off,
                                                 const int* flag, int force_f32x){
  bool f32in = flag[0] != 0;
  bool f32x  = force_f32x ? true : f32in;
  __shared__ float red[4];
  int row = blockIdx.x; int b = row >> 11;
  int d0 = threadIdx.x*4;
  float v[4]; ld4g(x, (size_t)row*D_ + d0, v, f32x);
  float ss = v[0]*v[0]+v[1]*v[1]+v[2]*v[2]+v[3]*v[3];
  float tot = blk_sum(ss, red);
  float r = rsqrtf(tot*(1.f/D_) + 1e-5f);
  const float* mb = m + b*6144;
  float wn[4]; ld4g(nw, d0, wn, f32in);
  float o[4];
  #pragma unroll
  for(int j=0;j<4;j++){
    int d = d0+j;
    o[j] = v[j]*r*wn[j]*(1.f+mb[scale_off+d]) + mb[shift_off+d];
  }
  st4(h + (size_t)row*D_ + d0, o);
}

__global__ __launch_bounds__(256) void k_ln_rope(u16* t, const void* w, const void* bb,
                                                 const void* fc, const void* fs, const int* flag){
  bool f32 = flag[0] != 0;
  __shared__ float red[4];
  int row = blockIdx.x; int s = row & (S_-1);
  int d0 = threadIdx.x*4;
  float v[4]; ld4(t + (size_t)row*D_ + d0, v);
  float sm = v[0]+v[1]+v[2]+v[3];
  float sq = v[0]*v[0]+v[1]*v[1]+v[2]*v[2]+v[3]*v[3];
  float tsm = blk_sum(sm, red);
  float tsq = blk_sum(sq, red);
  float mu  = tsm*(1.f/D_);
  float var = tsq*(1.f/D_) - mu*mu;
  float rs  = rsqrtf(var + 1e-5f);
  float wv[4], bv[4]; ld4g(w, d0, wv, f32); ld4g(bb, d0, bv, f32);
  float y[4];
  #pragma unroll
  for(int j=0;j<4;j++) y[j] = (v[j]-mu)*rs*wv[j] + bv[j];
  int pos = d0 & 63; int i0 = pos>>1;
  float c0 = ld1g(fc, s*32+i0,   f32), s0 = ld1g(fs, s*32+i0,   f32);
  float c1 = ld1g(fc, s*32+i0+1, f32), s1 = ld1g(fs, s*32+i0+1, f32);
  float o[4];
  o[0] = y[0]*c0 - y[1]*s0;
  o[1] = y[0]*s0 + y[1]*c0;
  o[2] = y[2]*c1 - y[3]*s1;
  o[3] = y[2]*s1 + y[3]*c1;
  st4(t + (size_t)row*D_ + d0, o);
}

// ---- weight transpose+cast: WT[N][K] bf16 <- W[K][N] (fp32 or bf16 per flag)
__global__ __launch_bounds__(256) void k_wt(const void* W, u16* WT, int Kd, int Nd,
                                            const int* flag){
  bool f32 = flag[0] != 0;
  __shared__ u16 L[64][72];
  int tid = threadIdx.x;
  int k0 = blockIdx.x*64, n0 = blockIdx.y*64;
  int r = tid>>2, c0 = (tid&3)*16;
  if(f32){
    const float* Wf = (const float*)W;
    #pragma unroll
    for(int j=0;j<4;j++){
      float4 t = *reinterpret_cast<const float4*>(&Wf[(size_t)(k0+r)*Nd + n0 + c0 + j*4]);
      L[r][c0+j*4+0]=f2bf(t.x); L[r][c0+j*4+1]=f2bf(t.y);
      L[r][c0+j*4+2]=f2bf(t.z); L[r][c0+j*4+3]=f2bf(t.w);
    }
  }else{
    const u16* Wh = (const u16*)W;
    *reinterpret_cast<short8*>(&L[r][c0]) =
      *reinterpret_cast<const short8*>(&Wh[(size_t)(k0+r)*Nd + n0 + c0]);
    *reinterpret_cast<short8*>(&L[r][c0+8]) =
      *reinterpret_cast<const short8*>(&Wh[(size_t)(k0+r)*Nd + n0 + c0 + 8]);
  }
  __syncthreads();
  int n = tid>>2, kk0 = (tid&3)*16;
  u16 tmp[16];
  #pragma unroll
  for(int j=0;j<16;j++) tmp[j] = L[kk0+j][n];
  u16* dst = WT + (size_t)(n0+n)*Kd + k0 + kk0;
  *reinterpret_cast<short8*>(dst)   = *reinterpret_cast<const short8*>(tmp);
  *reinterpret_cast<short8*>(dst+8) = *reinterpret_cast<const short8*>(tmp+8);
}

// ---- MFMA GEMM (m97 structure): C[M][N] = A[M][K] @ BT[N][K]^T, all bf16, fp32 acc.
// tile TM x 128, BK=32, global_load_lds staging, 2-barrier K-loop.
template<int TM>
__global__ __launch_bounds__(256) void k_gemm_mfma(const u16* A, const u16* BT, u16* C,
                                                   int M, int N, int K){
  __shared__ __align__(16) u16 As[TM*32];
  __shared__ __align__(16) u16 Bs[128*32];
  int tid = threadIdx.x, lane = tid&63, w = tid>>6;
  int col = lane&15, quad = lane>>4;
  int row0 = blockIdx.y*TM, col0 = blockIdx.x*128;
  const u16* Ab = A  + (size_t)row0*K;
  const u16* Bb = BT + (size_t)col0*K;
  constexpr int MI = 4;
  constexpr int NI = (TM==128)?4:2;
  int wm = (TM==128)? (w>>1)*64 : 0;
  int wn = (TM==128)? (w&1)*64 : w*32;
  f32x4 acc[MI][NI];
  #pragma unroll
  for(int i=0;i<MI;i++)
    #pragma unroll
    for(int j=0;j<NI;j++) acc[i][j] = (f32x4){0.f,0.f,0.f,0.f};

  for(int k0=0;k0<K;k0+=32){
    __syncthreads();
    #pragma unroll
    for(int i=0;i<TM*4/256;i++){
      int c = i*256 + w*64 + lane;
      gl2lds16(Ab + (size_t)(c>>2)*K + k0 + (c&3)*8, As + (size_t)(i*256 + w*64)*8);
    }
    #pragma unroll
    for(int i=0;i<2;i++){
      int c = i*256 + w*64 + lane;
      gl2lds16(Bb + (size_t)(c>>2)*K + k0 + (c&3)*8, Bs + (size_t)(i*256 + w*64)*8);
    }
    __syncthreads();
    short8 af[MI], bf[NI];
    #pragma unroll
    for(int mi=0;mi<MI;mi++)
      af[mi] = *reinterpret_cast<const short8*>(&As[(wm+mi*16+col)*32 + quad*8]);
    #pragma unroll
    for(int ni=0;ni<NI;ni++)
      bf[ni] = *reinterpret_cast<const short8*>(&Bs[(wn+ni*16+col)*32 + quad*8]);
    #pragma unroll
    for(int mi=0;mi<MI;mi++)
      #pragma unroll
      for(int ni=0;ni<NI;ni++)
        acc[mi][ni] = __builtin_amdgcn_mfma_f32_16x16x32_bf16(af[mi], bf[ni], acc[mi][ni], 0,0,0);
  }
  #pragma unroll
  for(int mi=0;mi<MI;mi++)
    #pragma unroll
    for(int r=0;r<4;r++){
      size_t rowoff = (size_t)(row0+wm+mi*16+quad*4+r)*N + col0 + wn;
      #pragma unroll
      for(int ni=0;ni<NI;ni++)
        C[rowoff + ni*16 + col] = f2bf(acc[mi][ni][r]);
    }
}

// ---- V transpose: vt[(b*H+h)][hd][key] <- v[(b*S+key)][h*64+hd]
__global__ __launch_bounds__(256) void k_vt(const u16* v, u16* vt){
  __shared__ u16 L[64][72];
  int tid = threadIdx.x;
  int wg = blockIdx.x;
  int kblk = wg & 31; int bh = wg >> 5; int h = bh & 15, b = bh >> 4;
  int row = tid>>2, c0 = (tid&3)*16;
  const u16* src = v + ((size_t)(b*S_ + kblk*64 + row))*D_ + h*HD_ + c0;
  *reinterpret_cast<short8*>(&L[row][c0])   = *reinterpret_cast<const short8*>(src);
  *reinterpret_cast<short8*>(&L[row][c0+8]) = *reinterpret_cast<const short8*>(src+8);
  __syncthreads();
  int hd = tid>>2, k0 = (tid&3)*16;
  u16 tmp[16];
  #pragma unroll
  for(int j=0;j<16;j++) tmp[j] = L[k0+j][hd];
  u16* dst = vt + ((size_t)bh*HD_ + hd)*S_ + kblk*64 + k0;
  *reinterpret_cast<short8*>(dst)   = *reinterpret_cast<const short8*>(tmp);
  *reinterpret_cast<short8*>(dst+8) = *reinterpret_cast<const short8*>(tmp+8);
}

// ---- MFMA flash attention (unchanged from round 3)
__global__ __launch_bounds__(256) void k_attn_mfma(const u16* q, const u16* k, const u16* vt,
                                                   u16* o){
  __shared__ u16 Ks[32][72];
  __shared__ u16 Vs[64][40];
  __shared__ u16 Ps[4][16][40];
  int tid = threadIdx.x, lane = tid & 63, wid = tid >> 6;
  int col = lane & 15, quad = lane >> 4;
  int wg = blockIdx.x;
  int qblk = wg & 31; int bh = wg >> 5; int h = bh & 15, b = bh >> 4;

  const u16* kb  = k  + ((size_t)b*S_)*D_ + h*HD_;
  const u16* vtb = vt + ((size_t)bh*HD_)*S_;

  short8 qa0, qa1;
  {
    const u16* qp = q + ((size_t)(b*S_ + qblk*64 + wid*16 + col))*D_ + h*HD_ + quad*8;
    qa0 = *reinterpret_cast<const short8*>(qp);
    qa1 = *reinterpret_cast<const short8*>(qp + 32);
  }
  float m_i[4], l_i[4];
  f32x4 acc[4];
  #pragma unroll
  for(int r=0;r<4;r++){ m_i[r]=-1e30f; l_i[r]=0.f; }
  #pragma unroll
  for(int t=0;t<4;t++) acc[t] = (f32x4){0.f,0.f,0.f,0.f};

  int srow = tid>>3, sc8 = (tid&7)*8;
  int vrow = tid>>2, vc8 = (tid&3)*8;

  for(int kc=0;kc<64;kc++){
    __syncthreads();
    *reinterpret_cast<short8*>(&Ks[srow][sc8]) =
      *reinterpret_cast<const short8*>(kb + (size_t)(kc*32 + srow)*D_ + sc8);
    *reinterpret_cast<short8*>(&Vs[vrow][vc8]) =
      *reinterpret_cast<const short8*>(vtb + (size_t)vrow*S_ + kc*32 + vc8);
    __syncthreads();

    f32x4 s0 = (f32x4){0.f,0.f,0.f,0.f}, s1 = s0;
    {
      short8 kb0 = *reinterpret_cast<const short8*>(&Ks[col][quad*8]);
      short8 kb1 = *reinterpret_cast<const short8*>(&Ks[col][quad*8+32]);
      short8 kb2 = *reinterpret_cast<const short8*>(&Ks[16+col][quad*8]);
      short8 kb3 = *reinterpret_cast<const short8*>(&Ks[16+col][quad*8+32]);
      s0 = __builtin_amdgcn_mfma_f32_16x16x32_bf16(qa0, kb0, s0, 0,0,0);
      s0 = __builtin_amdgcn_mfma_f32_16x16x32_bf16(qa1, kb1, s0, 0,0,0);
      s1 = __builtin_amdgcn_mfma_f32_16x16x32_bf16(qa0, kb2, s1, 0,0,0);
      s1 = __builtin_amdgcn_mfma_f32_16x16x32_bf16(qa1, kb3, s1, 0,0,0);
    }
    #pragma unroll
    for(int r=0;r<4;r++){
      float a = s0[r]*0.125f, c = s1[r]*0.125f;
      float cm = fmaxf(a, c);
      cm = fmaxf(cm, __shfl_xor(cm,1,64));
      cm = fmaxf(cm, __shfl_xor(cm,2,64));
      cm = fmaxf(cm, __shfl_xor(cm,4,64));
      cm = fmaxf(cm, __shfl_xor(cm,8,64));
      float mn = fmaxf(m_i[r], cm);
      float al = __expf(m_i[r]-mn);
      float p0 = __expf(a-mn), p1 = __expf(c-mn);
      float ps = p0+p1;
      ps += __shfl_xor(ps,1,64);
      ps += __shfl_xor(ps,2,64);
      ps += __shfl_xor(ps,4,64);
      ps += __shfl_xor(ps,8,64);
      l_i[r] = l_i[r]*al + ps;
      m_i[r] = mn;
      #pragma unroll
      for(int t=0;t<4;t++) acc[t][r] *= al;
      Ps[wid][quad*4+r][col]    = f2bf(p0);
      Ps[wid][quad*4+r][16+col] = f2bf(p1);
    }
    asm volatile("s_waitcnt lgkmcnt(0)" ::: "memory");
    short8 pa = *reinterpret_cast<const short8*>(&Ps[wid][col][quad*8]);
    #pragma unroll
    for(int t=0;t<4;t++){
      short8 vb = *reinterpret_cast<const short8*>(&Vs[t*16+col][quad*8]);
      acc[t] = __builtin_amdgcn_mfma_f32_16x16x32_bf16(pa, vb, acc[t], 0,0,0);
    }
  }
  int qrow = b*S_ + qblk*64 + wid*16 + quad*4;
  #pragma unroll
  for(int r=0;r<4;r++){
    float inv = 1.f/l_i[r];
    #pragma unroll
    for(int t=0;t<4;t++)
      o[(size_t)(qrow+r)*D_ + h*HD_ + t*16 + col] = f2bf(acc[t][r]*inv);
  }
}

__global__ __launch_bounds__(256) void k_resid_f(const void* x, const u16* y, const float* m,
                                                 int gate_off, float* o, const int* flag){
  bool f32 = flag[0] != 0;
  size_t i4 = ((size_t)blockIdx.x*256 + threadIdx.x)*4;
  int d = (int)(i4 & (D_-1));
  int b = (int)(i4 >> 21);
  float xv[4], yv[4];
  ld4g(x, i4, xv, f32); ld4(y+i4, yv);
  const float* g = m + b*6144 + gate_off + d;
  float4 r; r.x=xv[0]+g[0]*yv[0]; r.y=xv[1]+g[1]*yv[1]; r.z=xv[2]+g[2]*yv[2]; r.w=xv[3]+g[3]*yv[3];
  *reinterpret_cast<float4*>(o+i4) = r;
}

__global__ __launch_bounds__(256) void k_resid_b(const float* x, const u16* y, const float* m,
                                                 int gate_off, void* o, const int* flag){
  bool f32 = flag[0] != 0;
  size_t i4 = ((size_t)blockIdx.x*256 + threadIdx.x)*4;
  int d = (int)(i4 & (D_-1));
  int b = (int)(i4 >> 21);
  float xv[4], yv[4];
  ld4(x+i4, xv); ld4(y+i4, yv);
  const float* g = m + b*6144 + gate_off + d;
  float r[4];
  #pragma unroll
  for(int j=0;j<4;j++) r[j] = xv[j] + g[j]*yv[j];
  st4g(o, i4, r, f32);
}

__global__ __launch_bounds__(256) void k_silu_mul(const u16* h1, const u16* h3, u16* g){
  size_t i4 = ((size_t)blockIdx.x*256 + threadIdx.x)*4;
  float a[4], c[4];
  ld4(h1+i4, a); ld4(h3+i4, c);
  float r[4];
  #pragma unroll
  for(int j=0;j<4;j++){ float sv = a[j]/(1.f+__expf(-a[j])); r[j] = sv*c[j]; }
  st4(g+i4, r);
}

extern "C" void kernel_launch(void* const* d_in, const int* in_sizes, int n_in,
                              void* d_out, int out_size, void* d_ws, size_t ws_size,
                              hipStream_t stream){
  const void* x   = d_in[0];
  const void* ada = d_in[1];
  const void* fc  = d_in[2];
  const void* fs  = d_in[3];
  const void* wq  = d_in[4];
  const void* wk  = d_in[5];
  const void* wv  = d_in[6];
  const void* wo  = d_in[7];
  const void* qnw = d_in[8];
  const void* qnb = d_in[9];
  const void* knw = d_in[10];
  const void* knb = d_in[11];
  const void* anw = d_in[12];
  const void* fnw = d_in[13];
  const void* aw  = d_in[14];
  const void* ab  = d_in[15];
  const void* w1  = d_in[16];
  const void* w2  = d_in[17];
  const void* w3  = d_in[18];
  char* ws = (char*)d_ws;
  const size_t MB = 1u<<20;

  int*   flag = (int*)ws;                 // 4 B
  float* m    = (float*)(ws + 4096);      // 48 KB
  u16* hbuf   = (u16*)(ws + 1*MB);        // h -> attn -> h2
  u16* xq     = (u16*)(ws + 9*MB);        // xq -> proj -> ffn
  u16* xk     = (u16*)(ws + 17*MB);
  u16* xv     = (u16*)(ws + 25*MB);       // xv; later wtbig (w1T/w3T/w2T)
  u16* h1     = (u16*)(ws + 33*MB);       // vt alias; then h1/g
  u16* h3     = (u16*)(ws + 56*MB);       // wtq..wto early; then h3
  float* x2   = (float*)(ws + 79*MB);     // fp32 residual
  u16* vt    = h1;
  u16* attn  = hbuf;
  u16* h2    = hbuf;
  u16* proj  = xq;
  u16* ffn   = xq;
  u16* wtq   = (u16*)(ws + 56*MB);
  u16* wtk   = (u16*)(ws + 58*MB);
  u16* wtv   = (u16*)(ws + 60*MB);
  u16* wto   = (u16*)(ws + 62*MB);
  u16* wtbig = xv;    // 5.77 MB fits the 8 MB xv region; live only after k_vt

  dim3 blk(256);
  dim3 gD(8, 64);     // N=1024 GEMMs: TM=64
  dim3 gH(22, 32);    // N=2816 GEMMs: TM=128
  dim3 gW11(16, 16);  // k_wt 1024x1024
  dim3 gW1H(16, 44);  // k_wt K=1024, N=2816
  dim3 gWH1(44, 16);  // k_wt K=2816, N=1024

  k_probe<<<dim3(1), dim3(64), 0, stream>>>((const u16*)fc, flag);
  k_zero<<<dim3(48), blk, 0, stream>>>(m, 12288);
  k_adaln<<<dim3(24,8), blk, 0, stream>>>(ada, aw, ab, m, flag);
  k_rms_mod<<<dim3(B_*S_), blk, 0, stream>>>(x, anw, m, hbuf, 0, 1024, flag, 0);

  k_wt<<<gW11, blk, 0, stream>>>(wq, wtq, 1024, 1024, flag);
  k_wt<<<gW11, blk, 0, stream>>>(wk, wtk, 1024, 1024, flag);
  k_wt<<<gW11, blk, 0, stream>>>(wv, wtv, 1024, 1024, flag);
  k_gemm_mfma<64><<<gD, blk, 0, stream>>>(hbuf, wtq, xq, 4096, 1024, 1024);
  k_gemm_mfma<64><<<gD, blk, 0, stream>>>(hbuf, wtk, xk, 4096, 1024, 1024);
  k_gemm_mfma<64><<<gD, blk, 0, stream>>>(hbuf, wtv, xv, 4096, 1024, 1024);

  k_ln_rope<<<dim3(B_*S_), blk, 0, stream>>>(xq, qnw, qnb, fc, fs, flag);
  k_ln_rope<<<dim3(B_*S_), blk, 0, stream>>>(xk, knw, knb, fc, fs, flag);
  k_vt<<<dim3(B_*H_*S_/64), blk, 0, stream>>>(xv, vt);
  k_attn_mfma<<<dim3(B_*H_*S_/64), blk, 0, stream>>>(xq, xk, vt, attn);

  k_wt<<<gW11, blk, 0, stream>>>(wo, wto, 1024, 1024, flag);
  k_gemm_mfma<64><<<gD, blk, 0, stream>>>(attn, wto, proj, 4096, 1024, 1024);
  k_resid_f<<<dim3(4096), blk, 0, stream>>>(x, proj, m, 2048, x2, flag);
  k_rms_mod<<<dim3(B_*S_), blk, 0, stream>>>(x2, fnw, m, h2, 3072, 4096, flag, 1);

  k_wt<<<gW1H, blk, 0, stream>>>(w1, wtbig, 1024, 2816, flag);
  k_gemm_mfma<128><<<gH, blk, 0, stream>>>(h2, wtbig, h1, 4096, 2816, 1024);
  k_wt<<<gW1H, blk, 0, stream>>>(w3, wtbig, 1024, 2816, flag);
  k_gemm_mfma<128><<<gH, blk, 0, stream>>>(h2, wtbig, h3, 4096, 2816, 1024);
  k_silu_mul<<<dim3(11264), blk, 0, stream>>>(h1, h3, h1);
  k_wt<<<gWH1, blk, 0, stream>>>(w2, wtbig, 2816, 1024, flag);
  k_gemm_mfma<64><<<gD, blk, 0, stream>>>(h1, wtbig, ffn, 4096, 1024, 2816);
  k_resid_b<<<dim3(4096), blk, 0, stream>>>(x2, ffn, m, 5120, d_out, flag);
}

// Round 5
// 509.614 us; speedup vs baseline: 10.3063x; 1.2521x over previous
//
#include <hip/hip_runtime.h>
#include <hip/hip_bf16.h>

#define B_   2
#define S_   2048
#define D_   1024
#define H_   16
#define HD_  64
#define HID_ 2816

typedef unsigned short u16;
typedef unsigned int   u32;
typedef __attribute__((ext_vector_type(8))) short short8;
typedef __attribute__((ext_vector_type(4))) float f32x4;

static __device__ __forceinline__ float bf2f(u16 u){ return __uint_as_float(((u32)u)<<16); }
static __device__ __forceinline__ u16 f2bf(float f){
  u32 u = __float_as_uint(f);
  u32 r = (u + 0x7FFFu + ((u>>16)&1u)) >> 16;   // round-to-nearest-even
  return (u16)r;
}

static __device__ __forceinline__ void ld4(const u16* p, float* v){
  ushort4 t = *reinterpret_cast<const ushort4*>(p);
  v[0]=bf2f(t.x); v[1]=bf2f(t.y); v[2]=bf2f(t.z); v[3]=bf2f(t.w);
}
static __device__ __forceinline__ void ld4(const float* p, float* v){
  float4 t = *reinterpret_cast<const float4*>(p);
  v[0]=t.x; v[1]=t.y; v[2]=t.z; v[3]=t.w;
}
static __device__ __forceinline__ void st4(u16* p, const float* v){
  ushort4 t; t.x=f2bf(v[0]); t.y=f2bf(v[1]); t.z=f2bf(v[2]); t.w=f2bf(v[3]);
  *reinterpret_cast<ushort4*>(p)=t;
}

static __device__ __forceinline__ float ld1g(const void* p, size_t i, bool f32){
  return f32 ? ((const float*)p)[i] : bf2f(((const u16*)p)[i]);
}
static __device__ __forceinline__ void ld4g(const void* p, size_t i, float* v, bool f32){
  if(f32){
    float4 t = *reinterpret_cast<const float4*>((const float*)p + i);
    v[0]=t.x; v[1]=t.y; v[2]=t.z; v[3]=t.w;
  }else{
    ushort4 t = *reinterpret_cast<const ushort4*>((const u16*)p + i);
    v[0]=bf2f(t.x); v[1]=bf2f(t.y); v[2]=bf2f(t.z); v[3]=bf2f(t.w);
  }
}
static __device__ __forceinline__ void st4g(void* p, size_t i, const float* v, bool f32){
  if(f32){
    float4 t; t.x=v[0]; t.y=v[1]; t.z=v[2]; t.w=v[3];
    *reinterpret_cast<float4*>((float*)p + i) = t;
  }else{
    st4((u16*)p + i, v);
  }
}

// async global->LDS, 16B per lane; LDS dest = uniform base + lane*16
static __device__ __forceinline__ void gl2lds16(const u16* g, const u16* l){
  typedef __attribute__((address_space(3))) u16 lds_u16;
  typedef const __attribute__((address_space(1))) u16 glb_u16;
  __builtin_amdgcn_global_load_lds((glb_u16*)(uintptr_t)g,
                                   (lds_u16*)(u32)(uintptr_t)l, 16, 0, 0);
}

// ---- dtype probe: freqs_cos[0]==1.0f. fp32 -> first u16 is 0x0000; bf16 -> 0x3F80.
__global__ void k_probe(const u16* fc_raw, int* flag){
  if(threadIdx.x==0 && blockIdx.x==0) *flag = (fc_raw[0]==0) ? 1 : 0;
}

__global__ __launch_bounds__(256) void k_zero(float* p, int n){
  int i = blockIdx.x*256 + threadIdx.x;
  if(i<n) p[i] = 0.f;
}

static __device__ __forceinline__ float blk_sum(float v, float* red){
  #pragma unroll
  for(int o=32;o;o>>=1) v += __shfl_xor(v,o,64);
  int lane = threadIdx.x & 63, w = threadIdx.x >> 6;
  if(lane==0) red[w]=v;
  __syncthreads();
  float t = red[0]+red[1]+red[2]+red[3];
  __syncthreads();
  return t;
}

// ---- adaLN: m[b][n] = silu(a[b]) . ada_w[:,n] + ada_b[n]; K-split + atomicAdd (m pre-zeroed)
__global__ __launch_bounds__(256) void k_adaln(const void* a, const void* W, const void* bias,
                                               float* m, const int* flag){
  bool f32 = flag[0] != 0;
  __shared__ float sl[2][128];
  int bk = blockIdx.y;
  {
    int bb = threadIdx.x >> 7, kk = threadIdx.x & 127;
    float x = ld1g(a, bb*D_ + bk*128 + kk, f32);
    sl[bb][kk] = x/(1.f+__expf(-x));
  }
  __syncthreads();
  int n = blockIdx.x*256 + threadIdx.x;
  float p0 = 0.f, p1 = 0.f;
  for(int kk=0;kk<128;kk++){
    float w = ld1g(W, (size_t)(bk*128+kk)*6144 + n, f32);
    p0 += sl[0][kk]*w; p1 += sl[1][kk]*w;
  }
  if(bk==0){ float bv = ld1g(bias, n, f32); p0 += bv; p1 += bv; }
  atomicAdd(&m[n], p0);
  atomicAdd(&m[6144+n], p1);
}

__global__ __launch_bounds__(256) void k_rms_mod(const void* x, const void* nw, const float* m,
                                                 u16* h, int shift_off, int scale_off,
                                                 const int* flag, int force_f32x){
  bool f32in = flag[0] != 0;
  bool f32x  = force_f32x ? true : f32in;
  __shared__ float red[4];
  int row = blockIdx.x; int b = row >> 11;
  int d0 = threadIdx.x*4;
  float v[4]; ld4g(x, (size_t)row*D_ + d0, v, f32x);
  float ss = v[0]*v[0]+v[1]*v[1]+v[2]*v[2]+v[3]*v[3];
  float tot = blk_sum(ss, red);
  float r = rsqrtf(tot*(1.f/D_) + 1e-5f);
  const float* mb = m + b*6144;
  float wn[4]; ld4g(nw, d0, wn, f32in);
  float o[4];
  #pragma unroll
  for(int j=0;j<4;j++){
    int d = d0+j;
    o[j] = v[j]*r*wn[j]*(1.f+mb[scale_off+d]) + mb[shift_off+d];
  }
  st4(h + (size_t)row*D_ + d0, o);
}

// ---- layernorm + RoPE in place; t has row stride `str` (head slice of fused QKV)
__global__ __launch_bounds__(256) void k_ln_rope(u16* t, int str, const void* w, const void* bb,
                                                 const void* fc, const void* fs, const int* flag){
  bool f32 = flag[0] != 0;
  __shared__ float red[4];
  int row = blockIdx.x; int s = row & (S_-1);
  int d0 = threadIdx.x*4;
  u16* tp = t + (size_t)row*str + d0;
  float v[4]; ld4(tp, v);
  float sm = v[0]+v[1]+v[2]+v[3];
  float sq = v[0]*v[0]+v[1]*v[1]+v[2]*v[2]+v[3]*v[3];
  float tsm = blk_sum(sm, red);
  float tsq = blk_sum(sq, red);
  float mu  = tsm*(1.f/D_);
  float var = tsq*(1.f/D_) - mu*mu;
  float rs  = rsqrtf(var + 1e-5f);
  float wv[4], bv[4]; ld4g(w, d0, wv, f32); ld4g(bb, d0, bv, f32);
  float y[4];
  #pragma unroll
  for(int j=0;j<4;j++) y[j] = (v[j]-mu)*rs*wv[j] + bv[j];
  int pos = d0 & 63; int i0 = pos>>1;
  float c0 = ld1g(fc, s*32+i0,   f32), s0 = ld1g(fs, s*32+i0,   f32);
  float c1 = ld1g(fc, s*32+i0+1, f32), s1 = ld1g(fs, s*32+i0+1, f32);
  float o[4];
  o[0] = y[0]*c0 - y[1]*s0;
  o[1] = y[0]*s0 + y[1]*c0;
  o[2] = y[2]*c1 - y[3]*s1;
  o[3] = y[2]*s1 + y[3]*c1;
  st4(tp, o);
}

// ---- weight transpose+cast: WT[N][K] bf16 <- W[K][N]
__global__ __launch_bounds__(256) void k_wt(const void* W, u16* WT, int Kd, int Nd,
                                            const int* flag){
  bool f32 = flag[0] != 0;
  __shared__ u16 L[64][72];
  int tid = threadIdx.x;
  int k0 = blockIdx.x*64, n0 = blockIdx.y*64;
  int r = tid>>2, c0 = (tid&3)*16;
  if(f32){
    const float* Wf = (const float*)W;
    #pragma unroll
    for(int j=0;j<4;j++){
      float4 t = *reinterpret_cast<const float4*>(&Wf[(size_t)(k0+r)*Nd + n0 + c0 + j*4]);
      L[r][c0+j*4+0]=f2bf(t.x); L[r][c0+j*4+1]=f2bf(t.y);
      L[r][c0+j*4+2]=f2bf(t.z); L[r][c0+j*4+3]=f2bf(t.w);
    }
  }else{
    const u16* Wh = (const u16*)W;
    *reinterpret_cast<short8*>(&L[r][c0]) =
      *reinterpret_cast<const short8*>(&Wh[(size_t)(k0+r)*Nd + n0 + c0]);
    *reinterpret_cast<short8*>(&L[r][c0+8]) =
      *reinterpret_cast<const short8*>(&Wh[(size_t)(k0+r)*Nd + n0 + c0 + 8]);
  }
  __syncthreads();
  int n = tid>>2, kk0 = (tid&3)*16;
  u16 tmp[16];
  #pragma unroll
  for(int j=0;j<16;j++) tmp[j] = L[kk0+j][n];
  u16* dst = WT + (size_t)(n0+n)*Kd + k0 + kk0;
  *reinterpret_cast<short8*>(dst)   = *reinterpret_cast<const short8*>(tmp);
  *reinterpret_cast<short8*>(dst+8) = *reinterpret_cast<const short8*>(tmp+8);
}

// ---- MFMA GEMM, m97 structure: C[M][N] = A[M][K]@BT[N][K]^T; BK=64, TN=128, TM=128/64.
template<int TM>
__global__ __launch_bounds__(256) void k_gemm_mfma(const u16* A, int lda, const u16* BT, int ldb,
                                                   u16* C, int M, int N, int K){
  __shared__ __align__(16) u16 As[TM*64];
  __shared__ __align__(16) u16 Bs[128*64];
  int tid = threadIdx.x, lane = tid&63, w = tid>>6;
  int col = lane&15, quad = lane>>4;
  int row0 = blockIdx.y*TM, col0 = blockIdx.x*128;
  const u16* Ab = A  + (size_t)row0*lda;
  const u16* Bb = BT + (size_t)col0*ldb;
  constexpr int MI = TM/32;     // 4 (TM=128) or 2 (TM=64)
  int wm = (w>>1)*(TM/2);
  int wn = (w&1)*64;
  f32x4 acc[MI][4];
  #pragma unroll
  for(int i=0;i<MI;i++)
    #pragma unroll
    for(int j=0;j<4;j++) acc[i][j] = (f32x4){0.f,0.f,0.f,0.f};

  for(int k0=0;k0<K;k0+=64){
    __syncthreads();
    #pragma unroll
    for(int i=0;i<TM/32;i++){
      int c = i*256 + w*64 + lane;
      gl2lds16(Ab + (size_t)(c>>3)*lda + k0 + (c&7)*8, As + (size_t)c*8);
    }
    #pragma unroll
    for(int i=0;i<4;i++){
      int c = i*256 + w*64 + lane;
      gl2lds16(Bb + (size_t)(c>>3)*ldb + k0 + (c&7)*8, Bs + (size_t)c*8);
    }
    __syncthreads();
    #pragma unroll
    for(int ks=0;ks<64;ks+=32){
      short8 af[MI], bfr[4];
      #pragma unroll
      for(int mi=0;mi<MI;mi++)
        af[mi] = *reinterpret_cast<const short8*>(&As[(wm+mi*16+col)*64 + ks + quad*8]);
      #pragma unroll
      for(int ni=0;ni<4;ni++)
        bfr[ni] = *reinterpret_cast<const short8*>(&Bs[(wn+ni*16+col)*64 + ks + quad*8]);
      #pragma unroll
      for(int mi=0;mi<MI;mi++)
        #pragma unroll
        for(int ni=0;ni<4;ni++)
          acc[mi][ni] = __builtin_amdgcn_mfma_f32_16x16x32_bf16(af[mi], bfr[ni], acc[mi][ni], 0,0,0);
    }
  }
  #pragma unroll
  for(int mi=0;mi<MI;mi++)
    #pragma unroll
    for(int r=0;r<4;r++){
      size_t rowoff = (size_t)(row0+wm+mi*16+quad*4+r)*N + col0 + wn;
      #pragma unroll
      for(int ni=0;ni<4;ni++)
        C[rowoff + ni*16 + col] = f2bf(acc[mi][ni][r]);
    }
}

// ---- V transpose: vt[(b*H+h)][hd][key] <- v[(b*S+key)*vstr + h*64+hd]
__global__ __launch_bounds__(256) void k_vt(const u16* v, int vstr, u16* vt){
  __shared__ u16 L[64][72];
  int tid = threadIdx.x;
  int wg = blockIdx.x;
  int kblk = wg & 31; int bh = wg >> 5; int h = bh & 15, b = bh >> 4;
  int row = tid>>2, c0 = (tid&3)*16;
  const u16* src = v + (size_t)(b*S_ + kblk*64 + row)*vstr + h*HD_ + c0;
  *reinterpret_cast<short8*>(&L[row][c0])   = *reinterpret_cast<const short8*>(src);
  *reinterpret_cast<short8*>(&L[row][c0+8]) = *reinterpret_cast<const short8*>(src+8);
  __syncthreads();
  int hd = tid>>2, k0 = (tid&3)*16;
  u16 tmp[16];
  #pragma unroll
  for(int j=0;j<16;j++) tmp[j] = L[k0+j][hd];
  u16* dst = vt + ((size_t)bh*HD_ + hd)*S_ + kblk*64 + k0;
  *reinterpret_cast<short8*>(dst)   = *reinterpret_cast<const short8*>(tmp);
  *reinterpret_cast<short8*>(dst+8) = *reinterpret_cast<const short8*>(tmp+8);
}

// ---- MFMA flash attention v2: S^T scheme, key-permuted K staging, no P round-trip.
// q,k at stride qks (fused QKV); vt [bh][hd][key]; out compact stride D_.
__global__ __launch_bounds__(256) void k_attn_mfma(const u16* q, const u16* k, const u16* vt,
                                                   u16* o, int qks){
  __shared__ __align__(16) u16 Ks[64*88];   // row l holds key k(l), stride 88 -> 2-way banks
  __shared__ __align__(16) u16 Vs[64*88];   // row hd, natural key order
  int tid = threadIdx.x, lane = tid & 63, wid = tid >> 6;
  int col = lane & 15, quad = lane >> 4;
  int wg = blockIdx.x;
  int qblk = wg & 31; int bh = wg >> 5; int h = bh & 15, b = bh >> 4;

  const u16* kb  = k  + (size_t)b*S_*qks + h*HD_;
  const u16* vtb = vt + (size_t)bh*HD_*S_;

  short8 qa0, qa1;   // Q[q=col][d], pre-scaled by 1/8 (exact in bf16)
  {
    const u16* qp = q + (size_t)(b*S_ + qblk*64 + wid*16 + col)*qks + h*HD_ + quad*8;
    short8 t0 = *reinterpret_cast<const short8*>(qp);
    short8 t1 = *reinterpret_cast<const short8*>(qp + 32);
    #pragma unroll
    for(int j=0;j<8;j++){
      qa0[j] = (short)f2bf(bf2f((u16)t0[j])*0.125f);
      qa1[j] = (short)f2bf(bf2f((u16)t1[j])*0.125f);
    }
  }
  float m_i = -1e30f, l_i = 0.f;   // per-lane state for q=col (replicated across quads)
  f32x4 acc[4];
  #pragma unroll
  for(int t=0;t<4;t++) acc[t] = (f32x4){0.f,0.f,0.f,0.f};

  for(int t0=0;t0<S_;t0+=64){
    __syncthreads();
    #pragma unroll
    for(int g=0;g<2;g++){
      int c = g*256 + tid;
      int l = c>>3, kc = (c&7)*8;
      int kl = 32*(l>>5) + 8*((l>>2)&3) + 4*((l>>4)&1) + (l&3);  // key permutation
      *reinterpret_cast<short8*>(&Ks[l*88 + kc]) =
        *reinterpret_cast<const short8*>(kb + (size_t)(t0+kl)*qks + kc);
      *reinterpret_cast<short8*>(&Vs[l*88 + kc]) =
        *reinterpret_cast<const short8*>(vtb + (size_t)l*S_ + t0 + kc);
    }
    __syncthreads();

    // S^T[key][q]: 4 m-tiles of 16 keys; A = K rows (permuted), B = Q
    f32x4 st[4];
    #pragma unroll
    for(int mt=0;mt<4;mt++){
      st[mt] = (f32x4){0.f,0.f,0.f,0.f};
      short8 ka0 = *reinterpret_cast<const short8*>(&Ks[(mt*16+col)*88 + quad*8]);
      short8 ka1 = *reinterpret_cast<const short8*>(&Ks[(mt*16+col)*88 + 32 + quad*8]);
      st[mt] = __builtin_amdgcn_mfma_f32_16x16x32_bf16(ka0, qa0, st[mt], 0,0,0);
      st[mt] = __builtin_amdgcn_mfma_f32_16x16x32_bf16(ka1, qa1, st[mt], 0,0,0);
    }
    // online softmax: all reductions in-register + 2 shuffles (across quads)
    float cm = st[0][0];
    #pragma unroll
    for(int mt=0;mt<4;mt++)
      #pragma unroll
      for(int r=0;r<4;r++) cm = fmaxf(cm, st[mt][r]);
    cm = fmaxf(cm, __shfl_xor(cm,16,64));
    cm = fmaxf(cm, __shfl_xor(cm,32,64));
    float mn = fmaxf(m_i, cm);
    float al = __expf(m_i - mn);
    float pe[4][4]; float ps = 0.f;
    #pragma unroll
    for(int mt=0;mt<4;mt++)
      #pragma unroll
      for(int r=0;r<4;r++){ pe[mt][r] = __expf(st[mt][r]-mn); ps += pe[mt][r]; }
    ps += __shfl_xor(ps,16,64);
    ps += __shfl_xor(ps,32,64);
    l_i = l_i*al + ps;
    m_i = mn;
    #pragma unroll
    for(int t=0;t<4;t++) acc[t] *= al;
    // PV: O[q][hd] += P[q][key]·V[key][hd]; pb assembles lane-locally thanks to permutation
    #pragma unroll
    for(int w=0;w<2;w++){
      short8 pb;
      #pragma unroll
      for(int p=0;p<8;p++) pb[p] = (short)f2bf(pe[2*w + (p>>2)][p&3]);
      #pragma unroll
      for(int ht=0;ht<4;ht++){
        short8 vf = *reinterpret_cast<const short8*>(&Vs[(ht*16+col)*88 + w*32 + quad*8]);
        acc[ht] = __builtin_amdgcn_mfma_f32_16x16x32_bf16(vf, pb, acc[ht], 0,0,0);
      }
    }
  }
  // epilogue: acc[ht][r] = O[q=col][hd=ht*16+quad*4+r]
  float inv = 1.f/l_i;
  u16* ob = o + (size_t)(b*S_ + qblk*64 + wid*16 + col)*D_ + h*HD_;
  #pragma unroll
  for(int ht=0;ht<4;ht++){
    ushort4 t;
    t.x = f2bf(acc[ht][0]*inv); t.y = f2bf(acc[ht][1]*inv);
    t.z = f2bf(acc[ht][2]*inv); t.w = f2bf(acc[ht][3]*inv);
    *reinterpret_cast<ushort4*>(ob + ht*16 + quad*4) = t;
  }
}

__global__ __launch_bounds__(256) void k_resid_f(const void* x, const u16* y, const float* m,
                                                 int gate_off, float* o, const int* flag){
  bool f32 = flag[0] != 0;
  size_t i4 = ((size_t)blockIdx.x*256 + threadIdx.x)*4;
  int d = (int)(i4 & (D_-1));
  int b = (int)(i4 >> 21);
  float xv[4], yv[4];
  ld4g(x, i4, xv, f32); ld4(y+i4, yv);
  const float* g = m + b*6144 + gate_off + d;
  float4 r; r.x=xv[0]+g[0]*yv[0]; r.y=xv[1]+g[1]*yv[1]; r.z=xv[2]+g[2]*yv[2]; r.w=xv[3]+g[3]*yv[3];
  *reinterpret_cast<float4*>(o+i4) = r;
}

__global__ __launch_bounds__(256) void k_resid_b(const float* x, const u16* y, const float* m,
                                                 int gate_off, void* o, const int* flag){
  bool f32 = flag[0] != 0;
  size_t i4 = ((size_t)blockIdx.x*256 + threadIdx.x)*4;
  int d = (int)(i4 & (D_-1));
  int b = (int)(i4 >> 21);
  float xv[4], yv[4];
  ld4(x+i4, xv); ld4(y+i4, yv);
  const float* g = m + b*6144 + gate_off + d;
  float r[4];
  #pragma unroll
  for(int j=0;j<4;j++) r[j] = xv[j] + g[j]*yv[j];
  st4g(o, i4, r, f32);
}

// ---- silu(h1)*h3 in place over h1-half of fused h13 [4096][5632]
__global__ __launch_bounds__(256) void k_silu_mul(u16* h13){
  int c4 = (blockIdx.x*256 + threadIdx.x)*4;
  if(c4 >= HID_) return;
  u16* p = h13 + (size_t)blockIdx.y*5632 + c4;
  float a[4], c[4];
  ld4(p, a); ld4(p + HID_, c);
  float r[4];
  #pragma unroll
  for(int j=0;j<4;j++){ float sv = a[j]/(1.f+__expf(-a[j])); r[j] = sv*c[j]; }
  st4(p, r);
}

extern "C" void kernel_launch(void* const* d_in, const int* in_sizes, int n_in,
                              void* d_out, int out_size, void* d_ws, size_t ws_size,
                              hipStream_t stream){
  const void* x   = d_in[0];
  const void* ada = d_in[1];
  const void* fc  = d_in[2];
  const void* fs  = d_in[3];
  const void* wq  = d_in[4];
  const void* wk  = d_in[5];
  const void* wv  = d_in[6];
  const void* wo  = d_in[7];
  const void* qnw = d_in[8];
  const void* qnb = d_in[9];
  const void* knw = d_in[10];
  const void* knb = d_in[11];
  const void* anw = d_in[12];
  const void* fnw = d_in[13];
  const void* aw  = d_in[14];
  const void* ab  = d_in[15];
  const void* w1  = d_in[16];
  const void* w2  = d_in[17];
  const void* w3  = d_in[18];
  char* ws = (char*)d_ws;
  const size_t MB = 1u<<20;

  int*   flag = (int*)ws;
  float* m    = (float*)(ws + 4096);
  u16*  hbuf  = (u16*)(ws + 1*MB);     // h -> attn-out -> h2 (8MB)
  u16*  xqkv  = (u16*)(ws + 9*MB);     // [4096][3072] (24MB); dead after attn
  float* x2   = (float*)(ws + 9*MB);   // fp32 residual (16MB), aliases xqkv
  u16*  proj  = (u16*)(ws + 25*MB);    // proj/ffn (8MB), aliases xqkv tail
  u16*  wreg  = (u16*)(ws + 33*MB);    // 12MB: wqkvT -> vt -> wtoT -> wt13T -> w2T
  u16*  h13   = (u16*)(ws + 45*MB);    // [4096][5632] (44MB) -> ends 89MB
  u16*  vt    = wreg;

  dim3 blk(256);

  k_probe<<<dim3(1), dim3(64), 0, stream>>>((const u16*)fc, flag);
  k_zero<<<dim3(48), blk, 0, stream>>>(m, 12288);
  k_adaln<<<dim3(24,8), blk, 0, stream>>>(ada, aw, ab, m, flag);
  k_rms_mod<<<dim3(B_*S_), blk, 0, stream>>>(x, anw, m, hbuf, 0, 1024, flag, 0);

  // fused QKV
  k_wt<<<dim3(16,16), blk, 0, stream>>>(wq, wreg,                1024, 1024, flag);
  k_wt<<<dim3(16,16), blk, 0, stream>>>(wk, wreg + 1024*1024,    1024, 1024, flag);
  k_wt<<<dim3(16,16), blk, 0, stream>>>(wv, wreg + 2*1024*1024,  1024, 1024, flag);
  k_gemm_mfma<128><<<dim3(24,32), blk, 0, stream>>>(hbuf, 1024, wreg, 1024, xqkv, 4096, 3072, 1024);

  k_ln_rope<<<dim3(B_*S_), blk, 0, stream>>>(xqkv,        3072, qnw, qnb, fc, fs, flag);
  k_ln_rope<<<dim3(B_*S_), blk, 0, stream>>>(xqkv + 1024, 3072, knw, knb, fc, fs, flag);
  k_vt<<<dim3(B_*H_*S_/64), blk, 0, stream>>>(xqkv + 2048, 3072, vt);
  k_attn_mfma<<<dim3(B_*H_*S_/64), blk, 0, stream>>>(xqkv, xqkv + 1024, vt, hbuf, 3072);

  k_wt<<<dim3(16,16), blk, 0, stream>>>(wo, wreg, 1024, 1024, flag);
  k_gemm_mfma<64><<<dim3(8,64), blk, 0, stream>>>(hbuf, 1024, wreg, 1024, proj, 4096, 1024, 1024);
  k_resid_f<<<dim3(4096), blk, 0, stream>>>(x, proj, m, 2048, x2, flag);
  k_rms_mod<<<dim3(B_*S_), blk, 0, stream>>>(x2, fnw, m, hbuf, 3072, 4096, flag, 1);

  // fused w1|w3
  k_wt<<<dim3(16,44), blk, 0, stream>>>(w1, wreg,               1024, 2816, flag);
  k_wt<<<dim3(16,44), blk, 0, stream>>>(w3, wreg + 2816*1024,   1024, 2816, flag);
  k_gemm_mfma<128><<<dim3(44,32), blk, 0, stream>>>(hbuf, 1024, wreg, 1024, h13, 4096, 5632, 1024);
  k_silu_mul<<<dim3(3,4096), blk, 0, stream>>>(h13);
  k_wt<<<dim3(44,16), blk, 0, stream>>>(w2, wreg, 2816, 1024, flag);
  k_gemm_mfma<64><<<dim3(8,64), blk, 0, stream>>>(h13, 5632, wreg, 2816, proj, 4096, 1024, 2816);
  k_resid_b<<<dim3(4096), blk, 0, stream>>>(x2, proj, m, 5120, d_out, flag);
}

// Round 6
// 466.569 us; speedup vs baseline: 11.2571x; 1.0923x over previous
//
#include <hip/hip_runtime.h>
#include <hip/hip_bf16.h>

#define B_   2
#define S_   2048
#define D_   1024
#define H_   16
#define HD_  64
#define HID_ 2816

typedef unsigned short u16;
typedef unsigned int   u32;
typedef __attribute__((ext_vector_type(8))) short short8;
typedef __attribute__((ext_vector_type(4))) float f32x4;

static __device__ __forceinline__ float bf2f(u16 u){ return __uint_as_float(((u32)u)<<16); }
static __device__ __forceinline__ u16 f2bf(float f){
  u32 u = __float_as_uint(f);
  u32 r = (u + 0x7FFFu + ((u>>16)&1u)) >> 16;   // round-to-nearest-even
  return (u16)r;
}

static __device__ __forceinline__ void ld4(const u16* p, float* v){
  ushort4 t = *reinterpret_cast<const ushort4*>(p);
  v[0]=bf2f(t.x); v[1]=bf2f(t.y); v[2]=bf2f(t.z); v[3]=bf2f(t.w);
}
static __device__ __forceinline__ void ld4(const float* p, float* v){
  float4 t = *reinterpret_cast<const float4*>(p);
  v[0]=t.x; v[1]=t.y; v[2]=t.z; v[3]=t.w;
}
static __device__ __forceinline__ void st4(u16* p, const float* v){
  ushort4 t; t.x=f2bf(v[0]); t.y=f2bf(v[1]); t.z=f2bf(v[2]); t.w=f2bf(v[3]);
  *reinterpret_cast<ushort4*>(p)=t;
}

static __device__ __forceinline__ float ld1g(const void* p, size_t i, bool f32){
  return f32 ? ((const float*)p)[i] : bf2f(((const u16*)p)[i]);
}
static __device__ __forceinline__ void ld4g(const void* p, size_t i, float* v, bool f32){
  if(f32){
    float4 t = *reinterpret_cast<const float4*>((const float*)p + i);
    v[0]=t.x; v[1]=t.y; v[2]=t.z; v[3]=t.w;
  }else{
    ushort4 t = *reinterpret_cast<const ushort4*>((const u16*)p + i);
    v[0]=bf2f(t.x); v[1]=bf2f(t.y); v[2]=bf2f(t.z); v[3]=bf2f(t.w);
  }
}
static __device__ __forceinline__ void st4g(void* p, size_t i, const float* v, bool f32){
  if(f32){
    float4 t; t.x=v[0]; t.y=v[1]; t.z=v[2]; t.w=v[3];
    *reinterpret_cast<float4*>((float*)p + i) = t;
  }else{
    st4((u16*)p + i, v);
  }
}

// async global->LDS, 16B per lane; LDS dest = uniform base + lane*16
static __device__ __forceinline__ void gl2lds16(const u16* g, const u16* l){
  typedef __attribute__((address_space(3))) u16 lds_u16;
  typedef const __attribute__((address_space(1))) u16 glb_u16;
  __builtin_amdgcn_global_load_lds((glb_u16*)(uintptr_t)g,
                                   (lds_u16*)(u32)(uintptr_t)l, 16, 0, 0);
}

// ---- dtype probe: freqs_cos[0]==1.0f. fp32 -> first u16 is 0x0000; bf16 -> 0x3F80.
__global__ void k_probe(const u16* fc_raw, int* flag){
  if(threadIdx.x==0 && blockIdx.x==0) *flag = (fc_raw[0]==0) ? 1 : 0;
}

__global__ __launch_bounds__(256) void k_zero(float* p, int n){
  int i = blockIdx.x*256 + threadIdx.x;
  if(i<n) p[i] = 0.f;
}

static __device__ __forceinline__ float blk_sum(float v, float* red){
  #pragma unroll
  for(int o=32;o;o>>=1) v += __shfl_xor(v,o,64);
  int lane = threadIdx.x & 63, w = threadIdx.x >> 6;
  if(lane==0) red[w]=v;
  __syncthreads();
  float t = red[0]+red[1]+red[2]+red[3];
  __syncthreads();
  return t;
}

// ---- adaLN: m[b][n] = silu(a[b]) . ada_w[:,n] + ada_b[n]; K-split + atomicAdd (m pre-zeroed)
__global__ __launch_bounds__(256) void k_adaln(const void* a, const void* W, const void* bias,
                                               float* m, const int* flag){
  bool f32 = flag[0] != 0;
  __shared__ float sl[2][128];
  int bk = blockIdx.y;
  {
    int bb = threadIdx.x >> 7, kk = threadIdx.x & 127;
    float x = ld1g(a, bb*D_ + bk*128 + kk, f32);
    sl[bb][kk] = x/(1.f+__expf(-x));
  }
  __syncthreads();
  int n = blockIdx.x*256 + threadIdx.x;
  float p0 = 0.f, p1 = 0.f;
  for(int kk=0;kk<128;kk++){
    float w = ld1g(W, (size_t)(bk*128+kk)*6144 + n, f32);
    p0 += sl[0][kk]*w; p1 += sl[1][kk]*w;
  }
  if(bk==0){ float bv = ld1g(bias, n, f32); p0 += bv; p1 += bv; }
  atomicAdd(&m[n], p0);
  atomicAdd(&m[6144+n], p1);
}

__global__ __launch_bounds__(256) void k_rms_mod(const void* x, const void* nw, const float* m,
                                                 u16* h, int shift_off, int scale_off,
                                                 const int* flag, int force_f32x){
  bool f32in = flag[0] != 0;
  bool f32x  = force_f32x ? true : f32in;
  __shared__ float red[4];
  int row = blockIdx.x; int b = row >> 11;
  int d0 = threadIdx.x*4;
  float v[4]; ld4g(x, (size_t)row*D_ + d0, v, f32x);
  float ss = v[0]*v[0]+v[1]*v[1]+v[2]*v[2]+v[3]*v[3];
  float tot = blk_sum(ss, red);
  float r = rsqrtf(tot*(1.f/D_) + 1e-5f);
  const float* mb = m + b*6144;
  float wn[4]; ld4g(nw, d0, wn, f32in);
  float o[4];
  #pragma unroll
  for(int j=0;j<4;j++){
    int d = d0+j;
    o[j] = v[j]*r*wn[j]*(1.f+mb[scale_off+d]) + mb[shift_off+d];
  }
  st4(h + (size_t)row*D_ + d0, o);
}

// ---- layernorm + RoPE in place; t has row stride `str` (head slice of fused QKV)
__global__ __launch_bounds__(256) void k_ln_rope(u16* t, int str, const void* w, const void* bb,
                                                 const void* fc, const void* fs, const int* flag){
  bool f32 = flag[0] != 0;
  __shared__ float red[4];
  int row = blockIdx.x; int s = row & (S_-1);
  int d0 = threadIdx.x*4;
  u16* tp = t + (size_t)row*str + d0;
  float v[4]; ld4(tp, v);
  float sm = v[0]+v[1]+v[2]+v[3];
  float sq = v[0]*v[0]+v[1]*v[1]+v[2]*v[2]+v[3]*v[3];
  float tsm = blk_sum(sm, red);
  float tsq = blk_sum(sq, red);
  float mu  = tsm*(1.f/D_);
  float var = tsq*(1.f/D_) - mu*mu;
  float rs  = rsqrtf(var + 1e-5f);
  float wv[4], bv[4]; ld4g(w, d0, wv, f32); ld4g(bb, d0, bv, f32);
  float y[4];
  #pragma unroll
  for(int j=0;j<4;j++) y[j] = (v[j]-mu)*rs*wv[j] + bv[j];
  int pos = d0 & 63; int i0 = pos>>1;
  float c0 = ld1g(fc, s*32+i0,   f32), s0 = ld1g(fs, s*32+i0,   f32);
  float c1 = ld1g(fc, s*32+i0+1, f32), s1 = ld1g(fs, s*32+i0+1, f32);
  float o[4];
  o[0] = y[0]*c0 - y[1]*s0;
  o[1] = y[0]*s0 + y[1]*c0;
  o[2] = y[2]*c1 - y[3]*s1;
  o[3] = y[2]*s1 + y[3]*c1;
  st4(tp, o);
}

// ---- weight transpose+cast: WT[N][K] bf16 <- W[K][N]
__global__ __launch_bounds__(256) void k_wt(const void* W, u16* WT, int Kd, int Nd,
                                            const int* flag){
  bool f32 = flag[0] != 0;
  __shared__ u16 L[64][72];
  int tid = threadIdx.x;
  int k0 = blockIdx.x*64, n0 = blockIdx.y*64;
  int r = tid>>2, c0 = (tid&3)*16;
  if(f32){
    const float* Wf = (const float*)W;
    #pragma unroll
    for(int j=0;j<4;j++){
      float4 t = *reinterpret_cast<const float4*>(&Wf[(size_t)(k0+r)*Nd + n0 + c0 + j*4]);
      L[r][c0+j*4+0]=f2bf(t.x); L[r][c0+j*4+1]=f2bf(t.y);
      L[r][c0+j*4+2]=f2bf(t.z); L[r][c0+j*4+3]=f2bf(t.w);
    }
  }else{
    const u16* Wh = (const u16*)W;
    *reinterpret_cast<short8*>(&L[r][c0]) =
      *reinterpret_cast<const short8*>(&Wh[(size_t)(k0+r)*Nd + n0 + c0]);
    *reinterpret_cast<short8*>(&L[r][c0+8]) =
      *reinterpret_cast<const short8*>(&Wh[(size_t)(k0+r)*Nd + n0 + c0 + 8]);
  }
  __syncthreads();
  int n = tid>>2, kk0 = (tid&3)*16;
  u16 tmp[16];
  #pragma unroll
  for(int j=0;j<16;j++) tmp[j] = L[kk0+j][n];
  u16* dst = WT + (size_t)(n0+n)*Kd + k0 + kk0;
  *reinterpret_cast<short8*>(dst)   = *reinterpret_cast<const short8*>(tmp);
  *reinterpret_cast<short8*>(dst+8) = *reinterpret_cast<const short8*>(tmp+8);
}

// ---- MFMA GEMM, m97 structure + XOR-swizzled LDS (conflict-free frag reads).
// C[M][N] = A[M][K]@BT[N][K]^T; BK=64 (8x16B chunks/row), chunk slot = s ^ (row&7).
template<int TM>
__global__ __launch_bounds__(256) void k_gemm_mfma(const u16* A, int lda, const u16* BT, int ldb,
                                                   u16* C, int M, int N, int K){
  __shared__ __align__(16) u16 As[TM*64];
  __shared__ __align__(16) u16 Bs[128*64];
  int tid = threadIdx.x, lane = tid&63, w = tid>>6;
  int col = lane&15, quad = lane>>4;
  int row0 = blockIdx.y*TM, col0 = blockIdx.x*128;
  const u16* Ab = A  + (size_t)row0*lda;
  const u16* Bb = BT + (size_t)col0*ldb;
  constexpr int MI = TM/32;     // 4 (TM=128) or 2 (TM=64)
  int wm = (w>>1)*(TM/2);
  int wn = (w&1)*64;
  f32x4 acc[MI][4];
  #pragma unroll
  for(int i=0;i<MI;i++)
    #pragma unroll
    for(int j=0;j<4;j++) acc[i][j] = (f32x4){0.f,0.f,0.f,0.f};

  for(int k0=0;k0<K;k0+=64){
    __syncthreads();
    #pragma unroll
    for(int i=0;i<TM/32;i++){
      int c = i*256 + w*64 + lane;
      int r = c>>3, s = c&7, gs = s ^ (r&7);     // LDS slot s holds global chunk s^(r&7)
      gl2lds16(Ab + (size_t)r*lda + k0 + gs*8, As + (size_t)c*8);
    }
    #pragma unroll
    for(int i=0;i<4;i++){
      int c = i*256 + w*64 + lane;
      int r = c>>3, s = c&7, gs = s ^ (r&7);
      gl2lds16(Bb + (size_t)r*ldb + k0 + gs*8, Bs + (size_t)c*8);
    }
    __syncthreads();
    #pragma unroll
    for(int ks=0;ks<64;ks+=32){
      short8 af[MI], bfr[4];
      #pragma unroll
      for(int mi=0;mi<MI;mi++){
        int r = wm+mi*16+col;
        int sch = ((ks>>3) + quad) ^ (col&7);
        af[mi] = *reinterpret_cast<const short8*>(&As[r*64 + sch*8]);
      }
      #pragma unroll
      for(int ni=0;ni<4;ni++){
        int r = wn+ni*16+col;
        int sch = ((ks>>3) + quad) ^ (col&7);
        bfr[ni] = *reinterpret_cast<const short8*>(&Bs[r*64 + sch*8]);
      }
      #pragma unroll
      for(int mi=0;mi<MI;mi++)
        #pragma unroll
        for(int ni=0;ni<4;ni++)
          acc[mi][ni] = __builtin_amdgcn_mfma_f32_16x16x32_bf16(af[mi], bfr[ni], acc[mi][ni], 0,0,0);
    }
  }
  #pragma unroll
  for(int mi=0;mi<MI;mi++)
    #pragma unroll
    for(int r=0;r<4;r++){
      size_t rowoff = (size_t)(row0+wm+mi*16+quad*4+r)*N + col0 + wn;
      #pragma unroll
      for(int ni=0;ni<4;ni++)
        C[rowoff + ni*16 + col] = f2bf(acc[mi][ni][r]);
    }
}

// ---- V transpose: vt[(b*H+h)][hd][key] <- v[(b*S+key)*vstr + h*64+hd]
__global__ __launch_bounds__(256) void k_vt(const u16* v, int vstr, u16* vt){
  __shared__ u16 L[64][72];
  int tid = threadIdx.x;
  int wg = blockIdx.x;
  int kblk = wg & 31; int bh = wg >> 5; int h = bh & 15, b = bh >> 4;
  int row = tid>>2, c0 = (tid&3)*16;
  const u16* src = v + (size_t)(b*S_ + kblk*64 + row)*vstr + h*HD_ + c0;
  *reinterpret_cast<short8*>(&L[row][c0])   = *reinterpret_cast<const short8*>(src);
  *reinterpret_cast<short8*>(&L[row][c0+8]) = *reinterpret_cast<const short8*>(src+8);
  __syncthreads();
  int hd = tid>>2, k0 = (tid&3)*16;
  u16 tmp[16];
  #pragma unroll
  for(int j=0;j<16;j++) tmp[j] = L[k0+j][hd];
  u16* dst = vt + ((size_t)bh*HD_ + hd)*S_ + kblk*64 + k0;
  *reinterpret_cast<short8*>(dst)   = *reinterpret_cast<const short8*>(tmp);
  *reinterpret_cast<short8*>(dst+8) = *reinterpret_cast<const short8*>(tmp+8);
}

// ---- MFMA flash attention v2: S^T scheme, key-permuted K staging, no P round-trip.
__global__ __launch_bounds__(256) void k_attn_mfma(const u16* q, const u16* k, const u16* vt,
                                                   u16* o, int qks){
  __shared__ __align__(16) u16 Ks[64*88];   // row l holds key k(l), stride 88 -> 2-way banks
  __shared__ __align__(16) u16 Vs[64*88];   // row hd, natural key order
  int tid = threadIdx.x, lane = tid & 63, wid = tid >> 6;
  int col = lane & 15, quad = lane >> 4;
  int wg = blockIdx.x;
  int qblk = wg & 31; int bh = wg >> 5; int h = bh & 15, b = bh >> 4;

  const u16* kb  = k  + (size_t)b*S_*qks + h*HD_;
  const u16* vtb = vt + (size_t)bh*HD_*S_;

  short8 qa0, qa1;   // Q[q=col][d], pre-scaled by 1/8 (exact in bf16)
  {
    const u16* qp = q + (size_t)(b*S_ + qblk*64 + wid*16 + col)*qks + h*HD_ + quad*8;
    short8 t0 = *reinterpret_cast<const short8*>(qp);
    short8 t1 = *reinterpret_cast<const short8*>(qp + 32);
    #pragma unroll
    for(int j=0;j<8;j++){
      qa0[j] = (short)f2bf(bf2f((u16)t0[j])*0.125f);
      qa1[j] = (short)f2bf(bf2f((u16)t1[j])*0.125f);
    }
  }
  float m_i = -1e30f, l_i = 0.f;
  f32x4 acc[4];
  #pragma unroll
  for(int t=0;t<4;t++) acc[t] = (f32x4){0.f,0.f,0.f,0.f};

  for(int t0=0;t0<S_;t0+=64){
    __syncthreads();
    #pragma unroll
    for(int g=0;g<2;g++){
      int c = g*256 + tid;
      int l = c>>3, kc = (c&7)*8;
      int kl = 32*(l>>5) + 8*((l>>2)&3) + 4*((l>>4)&1) + (l&3);  // key permutation
      *reinterpret_cast<short8*>(&Ks[l*88 + kc]) =
        *reinterpret_cast<const short8*>(kb + (size_t)(t0+kl)*qks + kc);
      *reinterpret_cast<short8*>(&Vs[l*88 + kc]) =
        *reinterpret_cast<const short8*>(vtb + (size_t)l*S_ + t0 + kc);
    }
    __syncthreads();

    f32x4 st[4];
    #pragma unroll
    for(int mt=0;mt<4;mt++){
      st[mt] = (f32x4){0.f,0.f,0.f,0.f};
      short8 ka0 = *reinterpret_cast<const short8*>(&Ks[(mt*16+col)*88 + quad*8]);
      short8 ka1 = *reinterpret_cast<const short8*>(&Ks[(mt*16+col)*88 + 32 + quad*8]);
      st[mt] = __builtin_amdgcn_mfma_f32_16x16x32_bf16(ka0, qa0, st[mt], 0,0,0);
      st[mt] = __builtin_amdgcn_mfma_f32_16x16x32_bf16(ka1, qa1, st[mt], 0,0,0);
    }
    float cm = st[0][0];
    #pragma unroll
    for(int mt=0;mt<4;mt++)
      #pragma unroll
      for(int r=0;r<4;r++) cm = fmaxf(cm, st[mt][r]);
    cm = fmaxf(cm, __shfl_xor(cm,16,64));
    cm = fmaxf(cm, __shfl_xor(cm,32,64));
    float mn = fmaxf(m_i, cm);
    float al = __expf(m_i - mn);
    float pe[4][4]; float ps = 0.f;
    #pragma unroll
    for(int mt=0;mt<4;mt++)
      #pragma unroll
      for(int r=0;r<4;r++){ pe[mt][r] = __expf(st[mt][r]-mn); ps += pe[mt][r]; }
    ps += __shfl_xor(ps,16,64);
    ps += __shfl_xor(ps,32,64);
    l_i = l_i*al + ps;
    m_i = mn;
    #pragma unroll
    for(int t=0;t<4;t++) acc[t] *= al;
    #pragma unroll
    for(int w=0;w<2;w++){
      short8 pb;
      #pragma unroll
      for(int p=0;p<8;p++) pb[p] = (short)f2bf(pe[2*w + (p>>2)][p&3]);
      #pragma unroll
      for(int ht=0;ht<4;ht++){
        short8 vf = *reinterpret_cast<const short8*>(&Vs[(ht*16+col)*88 + w*32 + quad*8]);
        acc[ht] = __builtin_amdgcn_mfma_f32_16x16x32_bf16(vf, pb, acc[ht], 0,0,0);
      }
    }
  }
  float inv = 1.f/l_i;
  u16* ob = o + (size_t)(b*S_ + qblk*64 + wid*16 + col)*D_ + h*HD_;
  #pragma unroll
  for(int ht=0;ht<4;ht++){
    ushort4 t;
    t.x = f2bf(acc[ht][0]*inv); t.y = f2bf(acc[ht][1]*inv);
    t.z = f2bf(acc[ht][2]*inv); t.w = f2bf(acc[ht][3]*inv);
    *reinterpret_cast<ushort4*>(ob + ht*16 + quad*4) = t;
  }
}

__global__ __launch_bounds__(256) void k_resid_f(const void* x, const u16* y, const float* m,
                                                 int gate_off, float* o, const int* flag){
  bool f32 = flag[0] != 0;
  size_t i4 = ((size_t)blockIdx.x*256 + threadIdx.x)*4;
  int d = (int)(i4 & (D_-1));
  int b = (int)(i4 >> 21);
  float xv[4], yv[4];
  ld4g(x, i4, xv, f32); ld4(y+i4, yv);
  const float* g = m + b*6144 + gate_off + d;
  float4 r; r.x=xv[0]+g[0]*yv[0]; r.y=xv[1]+g[1]*yv[1]; r.z=xv[2]+g[2]*yv[2]; r.w=xv[3]+g[3]*yv[3];
  *reinterpret_cast<float4*>(o+i4) = r;
}

__global__ __launch_bounds__(256) void k_resid_b(const float* x, const u16* y, const float* m,
                                                 int gate_off, void* o, const int* flag){
  bool f32 = flag[0] != 0;
  size_t i4 = ((size_t)blockIdx.x*256 + threadIdx.x)*4;
  int d = (int)(i4 & (D_-1));
  int b = (int)(i4 >> 21);
  float xv[4], yv[4];
  ld4(x+i4, xv); ld4(y+i4, yv);
  const float* g = m + b*6144 + gate_off + d;
  float r[4];
  #pragma unroll
  for(int j=0;j<4;j++) r[j] = xv[j] + g[j]*yv[j];
  st4g(o, i4, r, f32);
}

// ---- silu(h1)*h3 in place over h1-half of fused h13 [4096][5632]
__global__ __launch_bounds__(256) void k_silu_mul(u16* h13){
  int c4 = (blockIdx.x*256 + threadIdx.x)*4;
  if(c4 >= HID_) return;
  u16* p = h13 + (size_t)blockIdx.y*5632 + c4;
  float a[4], c[4];
  ld4(p, a); ld4(p + HID_, c);
  float r[4];
  #pragma unroll
  for(int j=0;j<4;j++){ float sv = a[j]/(1.f+__expf(-a[j])); r[j] = sv*c[j]; }
  st4(p, r);
}

extern "C" void kernel_launch(void* const* d_in, const int* in_sizes, int n_in,
                              void* d_out, int out_size, void* d_ws, size_t ws_size,
                              hipStream_t stream){
  const void* x   = d_in[0];
  const void* ada = d_in[1];
  const void* fc  = d_in[2];
  const void* fs  = d_in[3];
  const void* wq  = d_in[4];
  const void* wk  = d_in[5];
  const void* wv  = d_in[6];
  const void* wo  = d_in[7];
  const void* qnw = d_in[8];
  const void* qnb = d_in[9];
  const void* knw = d_in[10];
  const void* knb = d_in[11];
  const void* anw = d_in[12];
  const void* fnw = d_in[13];
  const void* aw  = d_in[14];
  const void* ab  = d_in[15];
  const void* w1  = d_in[16];
  const void* w2  = d_in[17];
  const void* w3  = d_in[18];
  char* ws = (char*)d_ws;
  const size_t MB = 1u<<20;

  int*   flag = (int*)ws;
  float* m    = (float*)(ws + 4096);
  u16*  hbuf  = (u16*)(ws + 1*MB);     // h -> attn-out -> h2 (8MB)
  u16*  xqkv  = (u16*)(ws + 9*MB);     // [4096][3072] (24MB); dead after attn
  float* x2   = (float*)(ws + 9*MB);   // fp32 residual (16MB), aliases xqkv
  u16*  proj  = (u16*)(ws + 25*MB);    // proj/ffn (8MB), aliases xqkv tail
  u16*  wreg  = (u16*)(ws + 33*MB);    // 12MB: wqkvT -> vt -> wtoT -> wt13T -> w2T
  u16*  h13   = (u16*)(ws + 45*MB);    // [4096][5632] (44MB) -> ends 89MB
  u16*  vt    = wreg;

  dim3 blk(256);

  k_probe<<<dim3(1), dim3(64), 0, stream>>>((const u16*)fc, flag);
  k_zero<<<dim3(48), blk, 0, stream>>>(m, 12288);
  k_adaln<<<dim3(24,8), blk, 0, stream>>>(ada, aw, ab, m, flag);
  k_rms_mod<<<dim3(B_*S_), blk, 0, stream>>>(x, anw, m, hbuf, 0, 1024, flag, 0);

  // fused QKV
  k_wt<<<dim3(16,16), blk, 0, stream>>>(wq, wreg,                1024, 1024, flag);
  k_wt<<<dim3(16,16), blk, 0, stream>>>(wk, wreg + 1024*1024,    1024, 1024, flag);
  k_wt<<<dim3(16,16), blk, 0, stream>>>(wv, wreg + 2*1024*1024,  1024, 1024, flag);
  k_gemm_mfma<128><<<dim3(24,32), blk, 0, stream>>>(hbuf, 1024, wreg, 1024, xqkv, 4096, 3072, 1024);

  k_ln_rope<<<dim3(B_*S_), blk, 0, stream>>>(xqkv,        3072, qnw, qnb, fc, fs, flag);
  k_ln_rope<<<dim3(B_*S_), blk, 0, stream>>>(xqkv + 1024, 3072, knw, knb, fc, fs, flag);
  k_vt<<<dim3(B_*H_*S_/64), blk, 0, stream>>>(xqkv + 2048, 3072, vt);
  k_attn_mfma<<<dim3(B_*H_*S_/64), blk, 0, stream>>>(xqkv, xqkv + 1024, vt, hbuf, 3072);

  k_wt<<<dim3(16,16), blk, 0, stream>>>(wo, wreg, 1024, 1024, flag);
  k_gemm_mfma<64><<<dim3(8,64), blk, 0, stream>>>(hbuf, 1024, wreg, 1024, proj, 4096, 1024, 1024);
  k_resid_f<<<dim3(4096), blk, 0, stream>>>(x, proj, m, 2048, x2, flag);
  k_rms_mod<<<dim3(B_*S_), blk, 0, stream>>>(x2, fnw, m, hbuf, 3072, 4096, flag, 1);

  // fused w1|w3
  k_wt<<<dim3(16,44), blk, 0, stream>>>(w1, wreg,               1024, 2816, flag);
  k_wt<<<dim3(16,44), blk, 0, stream>>>(w3, wreg + 2816*1024,   1024, 2816, flag);
  k_gemm_mfma<128><<<dim3(44,32), blk, 0, stream>>>(hbuf, 1024, wreg, 1024, h13, 4096, 5632, 1024);
  k_silu_mul<<<dim3(3,4096), blk, 0, stream>>>(h13);
  k_wt<<<dim3(44,16), blk, 0, stream>>>(w2, wreg, 2816, 1024, flag);
  k_gemm_mfma<64><<<dim3(8,64), blk, 0, stream>>>(h13, 5632, wreg, 2816, proj, 4096, 1024, 2816);
  k_resid_b<<<dim3(4096), blk, 0, stream>>>(x2, proj, m, 5120, d_out, flag);
}

// Round 7
// 457.121 us; speedup vs baseline: 11.4898x; 1.0207x over previous
//
#include <hip/hip_runtime.h>
#include <hip/hip_bf16.h>

#define B_   2
#define S_   2048
#define D_   1024
#define H_   16
#define HD_  64
#define HID_ 2816

typedef unsigned short u16;
typedef unsigned int   u32;
typedef __attribute__((ext_vector_type(8))) short short8;
typedef __attribute__((ext_vector_type(4))) float f32x4;
typedef __attribute__((ext_vector_type(4))) u32   u32x4;

static __device__ __forceinline__ float bf2f(u16 u){ return __uint_as_float(((u32)u)<<16); }
static __device__ __forceinline__ u16 f2bf(float f){
  u32 u = __float_as_uint(f);
  u32 r = (u + 0x7FFFu + ((u>>16)&1u)) >> 16;   // round-to-nearest-even
  return (u16)r;
}
// round-half-up bf16 (2 ops) and packed pair (saves ~60% vs RNE)
static __device__ __forceinline__ u16 f2bfr(float f){
  return (u16)((__float_as_uint(f) + 0x8000u) >> 16);
}
static __device__ __forceinline__ u32 pk2(float a, float b){
  return ((__float_as_uint(a) + 0x8000u) >> 16) | ((__float_as_uint(b) + 0x8000u) & 0xFFFF0000u);
}

static __device__ __forceinline__ void ld4(const u16* p, float* v){
  ushort4 t = *reinterpret_cast<const ushort4*>(p);
  v[0]=bf2f(t.x); v[1]=bf2f(t.y); v[2]=bf2f(t.z); v[3]=bf2f(t.w);
}
static __device__ __forceinline__ void ld4(const float* p, float* v){
  float4 t = *reinterpret_cast<const float4*>(p);
  v[0]=t.x; v[1]=t.y; v[2]=t.z; v[3]=t.w;
}
static __device__ __forceinline__ void st4(u16* p, const float* v){
  ushort4 t; t.x=f2bf(v[0]); t.y=f2bf(v[1]); t.z=f2bf(v[2]); t.w=f2bf(v[3]);
  *reinterpret_cast<ushort4*>(p)=t;
}

static __device__ __forceinline__ float ld1g(const void* p, size_t i, bool f32){
  return f32 ? ((const float*)p)[i] : bf2f(((const u16*)p)[i]);
}
static __device__ __forceinline__ void ld4g(const void* p, size_t i, float* v, bool f32){
  if(f32){
    float4 t = *reinterpret_cast<const float4*>((const float*)p + i);
    v[0]=t.x; v[1]=t.y; v[2]=t.z; v[3]=t.w;
  }else{
    ushort4 t = *reinterpret_cast<const ushort4*>((const u16*)p + i);
    v[0]=bf2f(t.x); v[1]=bf2f(t.y); v[2]=bf2f(t.z); v[3]=bf2f(t.w);
  }
}
static __device__ __forceinline__ void st4g(void* p, size_t i, const float* v, bool f32){
  if(f32){
    float4 t; t.x=v[0]; t.y=v[1]; t.z=v[2]; t.w=v[3];
    *reinterpret_cast<float4*>((float*)p + i) = t;
  }else{
    st4((u16*)p + i, v);
  }
}

// async global->LDS, 16B per lane; LDS dest = uniform base + lane*16
static __device__ __forceinline__ void gl2lds16(const u16* g, const u16* l){
  typedef __attribute__((address_space(3))) u16 lds_u16;
  typedef const __attribute__((address_space(1))) u16 glb_u16;
  __builtin_amdgcn_global_load_lds((glb_u16*)(uintptr_t)g,
                                   (lds_u16*)(u32)(uintptr_t)l, 16, 0, 0);
}

// ---- probe (freqs_cos[0]==1.0f -> fp32 first u16 is 0) + zero m
__global__ __launch_bounds__(256) void k_probe_zero(const u16* fc_raw, int* flag, float* m){
  int i = blockIdx.x*256 + threadIdx.x;
  if(i < 12288) m[i] = 0.f;
  if(i == 0) *flag = (fc_raw[0]==0) ? 1 : 0;
}

static __device__ __forceinline__ float blk_sum(float v, float* red){
  #pragma unroll
  for(int o=32;o;o>>=1) v += __shfl_xor(v,o,64);
  int lane = threadIdx.x & 63, w = threadIdx.x >> 6;
  if(lane==0) red[w]=v;
  __syncthreads();
  float t = red[0]+red[1]+red[2]+red[3];
  __syncthreads();
  return t;
}

// ---- adaLN: m[b][n] = silu(a[b]) . ada_w[:,n] + ada_b[n]; K-split + atomicAdd (m pre-zeroed)
__global__ __launch_bounds__(256) void k_adaln(const void* a, const void* W, const void* bias,
                                               float* m, const int* flag){
  bool f32 = flag[0] != 0;
  __shared__ float sl[2][128];
  int bk = blockIdx.y;
  {
    int bb = threadIdx.x >> 7, kk = threadIdx.x & 127;
    float x = ld1g(a, bb*D_ + bk*128 + kk, f32);
    sl[bb][kk] = x/(1.f+__expf(-x));
  }
  __syncthreads();
  int n = blockIdx.x*256 + threadIdx.x;
  float p0 = 0.f, p1 = 0.f;
  for(int kk=0;kk<128;kk++){
    float w = ld1g(W, (size_t)(bk*128+kk)*6144 + n, f32);
    p0 += sl[0][kk]*w; p1 += sl[1][kk]*w;
  }
  if(bk==0){ float bv = ld1g(bias, n, f32); p0 += bv; p1 += bv; }
  atomicAdd(&m[n], p0);
  atomicAdd(&m[6144+n], p1);
}

__global__ __launch_bounds__(256) void k_rms_mod(const void* x, const void* nw, const float* m,
                                                 u16* h, int shift_off, int scale_off,
                                                 const int* flag){
  bool f32 = flag[0] != 0;
  __shared__ float red[4];
  int row = blockIdx.x; int b = row >> 11;
  int d0 = threadIdx.x*4;
  float v[4]; ld4g(x, (size_t)row*D_ + d0, v, f32);
  float ss = v[0]*v[0]+v[1]*v[1]+v[2]*v[2]+v[3]*v[3];
  float tot = blk_sum(ss, red);
  float r = rsqrtf(tot*(1.f/D_) + 1e-5f);
  const float* mb = m + b*6144;
  float wn[4]; ld4g(nw, d0, wn, f32);
  float o[4];
  #pragma unroll
  for(int j=0;j<4;j++){
    int d = d0+j;
    o[j] = v[j]*r*wn[j]*(1.f+mb[scale_off+d]) + mb[shift_off+d];
  }
  st4(h + (size_t)row*D_ + d0, o);
}

// ---- fused: x2 = x + gate_msa*proj (fp32 out), then h2 = rmsnorm(x2)*(1+scale_mlp)+shift_mlp
__global__ __launch_bounds__(256) void k_resid_rms(const void* x, const u16* y, const float* m,
                                                   const void* nw, float* x2, u16* h,
                                                   const int* flag){
  bool f32 = flag[0] != 0;
  __shared__ float red[4];
  int row = blockIdx.x; int b = row >> 11;
  int d0 = threadIdx.x*4;
  size_t i4 = (size_t)row*D_ + d0;
  float xv[4], yv[4];
  ld4g(x, i4, xv, f32); ld4(y+i4, yv);
  const float* mb = m + b*6144;
  float v[4];
  #pragma unroll
  for(int j=0;j<4;j++) v[j] = xv[j] + mb[2048+d0+j]*yv[j];
  float4 t; t.x=v[0]; t.y=v[1]; t.z=v[2]; t.w=v[3];
  *reinterpret_cast<float4*>(x2+i4) = t;
  float ss = v[0]*v[0]+v[1]*v[1]+v[2]*v[2]+v[3]*v[3];
  float tot = blk_sum(ss, red);
  float r = rsqrtf(tot*(1.f/D_) + 1e-5f);
  float wn[4]; ld4g(nw, d0, wn, f32);
  float o[4];
  #pragma unroll
  for(int j=0;j<4;j++)
    o[j] = v[j]*r*wn[j]*(1.f+mb[4096+d0+j]) + mb[3072+d0+j];
  st4(h + i4, o);
}

// ---- layernorm + RoPE in place over q (y=0) and k (y=1) head slices of fused QKV
__global__ __launch_bounds__(256) void k_ln_rope2(u16* t, const void* qw, const void* qb,
                                                  const void* kw, const void* kb2,
                                                  const void* fc, const void* fs, const int* flag){
  bool f32 = flag[0] != 0;
  __shared__ float red[4];
  int row = blockIdx.x; int s = row & (S_-1);
  const void* w  = blockIdx.y ? kw  : qw;
  const void* bb = blockIdx.y ? kb2 : qb;
  int d0 = threadIdx.x*4;
  u16* tp = t + (size_t)row*3072 + blockIdx.y*1024 + d0;
  float v[4]; ld4(tp, v);
  float sm = v[0]+v[1]+v[2]+v[3];
  float sq = v[0]*v[0]+v[1]*v[1]+v[2]*v[2]+v[3]*v[3];
  float tsm = blk_sum(sm, red);
  float tsq = blk_sum(sq, red);
  float mu  = tsm*(1.f/D_);
  float var = tsq*(1.f/D_) - mu*mu;
  float rs  = rsqrtf(var + 1e-5f);
  float wv[4], bv[4]; ld4g(w, d0, wv, f32); ld4g(bb, d0, bv, f32);
  float y[4];
  #pragma unroll
  for(int j=0;j<4;j++) y[j] = (v[j]-mu)*rs*wv[j] + bv[j];
  int pos = d0 & 63; int i0 = pos>>1;
  float c0 = ld1g(fc, s*32+i0,   f32), s0 = ld1g(fs, s*32+i0,   f32);
  float c1 = ld1g(fc, s*32+i0+1, f32), s1 = ld1g(fs, s*32+i0+1, f32);
  float o[4];
  o[0] = y[0]*c0 - y[1]*s0;
  o[1] = y[0]*s0 + y[1]*c0;
  o[2] = y[2]*c1 - y[3]*s1;
  o[3] = y[2]*s1 + y[3]*c1;
  st4(tp, o);
}

// ---- weight transpose+cast, multi-source: z selects W0/W1/W2; dst offset z*Kd*Nd
__global__ __launch_bounds__(256) void k_wt3(const void* W0, const void* W1, const void* W2,
                                             u16* WT, int Kd, int Nd, const int* flag){
  bool f32 = flag[0] != 0;
  const void* W = blockIdx.z==0 ? W0 : (blockIdx.z==1 ? W1 : W2);
  u16* dst_base = WT + (size_t)blockIdx.z * (size_t)Kd * Nd;
  __shared__ u16 L[64][72];
  int tid = threadIdx.x;
  int k0 = blockIdx.x*64, n0 = blockIdx.y*64;
  int r = tid>>2, c0 = (tid&3)*16;
  if(f32){
    const float* Wf = (const float*)W;
    #pragma unroll
    for(int j=0;j<4;j++){
      float4 t = *reinterpret_cast<const float4*>(&Wf[(size_t)(k0+r)*Nd + n0 + c0 + j*4]);
      L[r][c0+j*4+0]=f2bfr(t.x); L[r][c0+j*4+1]=f2bfr(t.y);
      L[r][c0+j*4+2]=f2bfr(t.z); L[r][c0+j*4+3]=f2bfr(t.w);
    }
  }else{
    const u16* Wh = (const u16*)W;
    *reinterpret_cast<short8*>(&L[r][c0]) =
      *reinterpret_cast<const short8*>(&Wh[(size_t)(k0+r)*Nd + n0 + c0]);
    *reinterpret_cast<short8*>(&L[r][c0+8]) =
      *reinterpret_cast<const short8*>(&Wh[(size_t)(k0+r)*Nd + n0 + c0 + 8]);
  }
  __syncthreads();
  int n = tid>>2, kk0 = (tid&3)*16;
  u16 tmp[16];
  #pragma unroll
  for(int j=0;j<16;j++) tmp[j] = L[kk0+j][n];
  u16* dst = dst_base + (size_t)(n0+n)*Kd + k0 + kk0;
  *reinterpret_cast<short8*>(dst)   = *reinterpret_cast<const short8*>(tmp);
  *reinterpret_cast<short8*>(dst+8) = *reinterpret_cast<const short8*>(tmp+8);
}

// ---- MFMA GEMM, m97 structure + XOR-swizzled LDS (conflict-minimal frag reads).
template<int TM>
__global__ __launch_bounds__(256) void k_gemm_mfma(const u16* A, int lda, const u16* BT, int ldb,
                                                   u16* C, int M, int N, int K){
  __shared__ __align__(16) u16 As[TM*64];
  __shared__ __align__(16) u16 Bs[128*64];
  int tid = threadIdx.x, lane = tid&63, w = tid>>6;
  int col = lane&15, quad = lane>>4;
  int row0 = blockIdx.y*TM, col0 = blockIdx.x*128;
  const u16* Ab = A  + (size_t)row0*lda;
  const u16* Bb = BT + (size_t)col0*ldb;
  constexpr int MI = TM/32;
  int wm = (w>>1)*(TM/2);
  int wn = (w&1)*64;
  f32x4 acc[MI][4];
  #pragma unroll
  for(int i=0;i<MI;i++)
    #pragma unroll
    for(int j=0;j<4;j++) acc[i][j] = (f32x4){0.f,0.f,0.f,0.f};

  for(int k0=0;k0<K;k0+=64){
    __syncthreads();
    #pragma unroll
    for(int i=0;i<TM/32;i++){
      int c = i*256 + w*64 + lane;
      int r = c>>3, s = c&7, gs = s ^ (r&7);
      gl2lds16(Ab + (size_t)r*lda + k0 + gs*8, As + (size_t)c*8);
    }
    #pragma unroll
    for(int i=0;i<4;i++){
      int c = i*256 + w*64 + lane;
      int r = c>>3, s = c&7, gs = s ^ (r&7);
      gl2lds16(Bb + (size_t)r*ldb + k0 + gs*8, Bs + (size_t)c*8);
    }
    __syncthreads();
    #pragma unroll
    for(int ks=0;ks<64;ks+=32){
      short8 af[MI], bfr[4];
      #pragma unroll
      for(int mi=0;mi<MI;mi++){
        int r = wm+mi*16+col;
        int sch = ((ks>>3) + quad) ^ (col&7);
        af[mi] = *reinterpret_cast<const short8*>(&As[r*64 + sch*8]);
      }
      #pragma unroll
      for(int ni=0;ni<4;ni++){
        int r = wn+ni*16+col;
        int sch = ((ks>>3) + quad) ^ (col&7);
        bfr[ni] = *reinterpret_cast<const short8*>(&Bs[r*64 + sch*8]);
      }
      #pragma unroll
      for(int mi=0;mi<MI;mi++)
        #pragma unroll
        for(int ni=0;ni<4;ni++)
          acc[mi][ni] = __builtin_amdgcn_mfma_f32_16x16x32_bf16(af[mi], bfr[ni], acc[mi][ni], 0,0,0);
    }
  }
  #pragma unroll
  for(int mi=0;mi<MI;mi++)
    #pragma unroll
    for(int r=0;r<4;r++){
      size_t rowoff = (size_t)(row0+wm+mi*16+quad*4+r)*N + col0 + wn;
      #pragma unroll
      for(int ni=0;ni<4;ni++)
        C[rowoff + ni*16 + col] = f2bfr(acc[mi][ni][r]);
    }
}

// ---- V transpose: vt[(b*H+h)][hd][key] <- v[(b*S+key)*vstr + h*64+hd]
__global__ __launch_bounds__(256) void k_vt(const u16* v, int vstr, u16* vt){
  __shared__ u16 L[64][72];
  int tid = threadIdx.x;
  int wg = blockIdx.x;
  int kblk = wg & 31; int bh = wg >> 5; int h = bh & 15, b = bh >> 4;
  int row = tid>>2, c0 = (tid&3)*16;
  const u16* src = v + (size_t)(b*S_ + kblk*64 + row)*vstr + h*HD_ + c0;
  *reinterpret_cast<short8*>(&L[row][c0])   = *reinterpret_cast<const short8*>(src);
  *reinterpret_cast<short8*>(&L[row][c0+8]) = *reinterpret_cast<const short8*>(src+8);
  __syncthreads();
  int hd = tid>>2, k0 = (tid&3)*16;
  u16 tmp[16];
  #pragma unroll
  for(int j=0;j<16;j++) tmp[j] = L[k0+j][hd];
  u16* dst = vt + ((size_t)bh*HD_ + hd)*S_ + kblk*64 + k0;
  *reinterpret_cast<short8*>(dst)   = *reinterpret_cast<const short8*>(tmp);
  *reinterpret_cast<short8*>(dst+8) = *reinterpret_cast<const short8*>(tmp+8);
}

// ---- MFMA flash attention v3: S^T scheme, exp2 domain, packed rhu bf16, PV before l-sum.
__global__ __launch_bounds__(256) void k_attn_mfma(const u16* q, const u16* k, const u16* vt,
                                                   u16* o, int qks){
  __shared__ __align__(16) u16 Ks[64*88];
  __shared__ __align__(16) u16 Vs[64*88];
  int tid = threadIdx.x, lane = tid & 63, wid = tid >> 6;
  int col = lane & 15, quad = lane >> 4;
  int wg = blockIdx.x;
  int qblk = wg & 31; int bh = wg >> 5; int h = bh & 15, b = bh >> 4;

  const u16* kb  = k  + (size_t)b*S_*qks + h*HD_;
  const u16* vtb = vt + (size_t)bh*HD_*S_;

  short8 qa0, qa1;   // Q[q=col][d], pre-scaled by 0.125*log2(e) -> scores in log2 domain
  {
    const float qscale = 0.18033688f;
    const u16* qp = q + (size_t)(b*S_ + qblk*64 + wid*16 + col)*qks + h*HD_ + quad*8;
    short8 t0 = *reinterpret_cast<const short8*>(qp);
    short8 t1 = *reinterpret_cast<const short8*>(qp + 32);
    #pragma unroll
    for(int j=0;j<8;j++){
      qa0[j] = (short)f2bf(bf2f((u16)t0[j])*qscale);
      qa1[j] = (short)f2bf(bf2f((u16)t1[j])*qscale);
    }
  }
  float m_i = -1e30f, l_i = 0.f;
  f32x4 acc[4];
  #pragma unroll
  for(int t=0;t<4;t++) acc[t] = (f32x4){0.f,0.f,0.f,0.f};

  // hoisted staging pointers (2 chunks of 256 lanes each)
  const u16 *kp[2]; const u16 *vp[2]; u16 *ksd[2], *vsd[2];
  #pragma unroll
  for(int g=0;g<2;g++){
    int c = g*256 + tid;
    int l = c>>3, kc = (c&7)*8;
    int kl = 32*(l>>5) + 8*((l>>2)&3) + 4*((l>>4)&1) + (l&3);
    kp[g]  = kb + (size_t)kl*qks + kc;
    vp[g]  = vtb + (size_t)l*S_ + kc;
    ksd[g] = Ks + l*88 + kc;
    vsd[g] = Vs + l*88 + kc;
  }

  for(int t0=0;t0<S_;t0+=64){
    __syncthreads();
    #pragma unroll
    for(int g=0;g<2;g++){
      *reinterpret_cast<short8*>(ksd[g]) =
        *reinterpret_cast<const short8*>(kp[g] + (size_t)t0*qks);
      *reinterpret_cast<short8*>(vsd[g]) =
        *reinterpret_cast<const short8*>(vp[g] + t0);
    }
    __syncthreads();

    f32x4 st[4];
    #pragma unroll
    for(int mt=0;mt<4;mt++){
      st[mt] = (f32x4){0.f,0.f,0.f,0.f};
      short8 ka0 = *reinterpret_cast<const short8*>(&Ks[(mt*16+col)*88 + quad*8]);
      short8 ka1 = *reinterpret_cast<const short8*>(&Ks[(mt*16+col)*88 + 32 + quad*8]);
      st[mt] = __builtin_amdgcn_mfma_f32_16x16x32_bf16(ka0, qa0, st[mt], 0,0,0);
      st[mt] = __builtin_amdgcn_mfma_f32_16x16x32_bf16(ka1, qa1, st[mt], 0,0,0);
    }
    float cm = st[0][0];
    #pragma unroll
    for(int mt=0;mt<4;mt++)
      #pragma unroll
      for(int r=0;r<4;r++) cm = fmaxf(cm, st[mt][r]);
    cm = fmaxf(cm, __shfl_xor(cm,16,64));
    cm = fmaxf(cm, __shfl_xor(cm,32,64));
    float mn = fmaxf(m_i, cm);
    float al = __builtin_amdgcn_exp2f(m_i - mn);
    m_i = mn;
    float pe[4][4];
    #pragma unroll
    for(int mt=0;mt<4;mt++)
      #pragma unroll
      for(int r=0;r<4;r++) pe[mt][r] = __builtin_amdgcn_exp2f(st[mt][r]-mn);
    #pragma unroll
    for(int t=0;t<4;t++) acc[t] *= al;
    // PV first (l-sum not needed by it)
    #pragma unroll
    for(int w=0;w<2;w++){
      u32x4 pw;
      pw[0] = pk2(pe[2*w][0],   pe[2*w][1]);
      pw[1] = pk2(pe[2*w][2],   pe[2*w][3]);
      pw[2] = pk2(pe[2*w+1][0], pe[2*w+1][1]);
      pw[3] = pk2(pe[2*w+1][2], pe[2*w+1][3]);
      short8 pb = *reinterpret_cast<short8*>(&pw);
      #pragma unroll
      for(int ht=0;ht<4;ht++){
        short8 vf = *reinterpret_cast<const short8*>(&Vs[(ht*16+col)*88 + w*32 + quad*8]);
        acc[ht] = __builtin_amdgcn_mfma_f32_16x16x32_bf16(vf, pb, acc[ht], 0,0,0);
      }
    }
    float ps = 0.f;
    #pragma unroll
    for(int mt=0;mt<4;mt++)
      #pragma unroll
      for(int r=0;r<4;r++) ps += pe[mt][r];
    ps += __shfl_xor(ps,16,64);
    ps += __shfl_xor(ps,32,64);
    l_i = l_i*al + ps;
  }
  float inv = __builtin_amdgcn_rcpf(l_i);
  u16* ob = o + (size_t)(b*S_ + qblk*64 + wid*16 + col)*D_ + h*HD_;
  #pragma unroll
  for(int ht=0;ht<4;ht++){
    uint2 t;
    t.x = pk2(acc[ht][0]*inv, acc[ht][1]*inv);
    t.y = pk2(acc[ht][2]*inv, acc[ht][3]*inv);
    *reinterpret_cast<uint2*>(ob + ht*16 + quad*4) = t;
  }
}

// ---- out = x2 + gate_mlp*ffn -> harness output dtype
__global__ __launch_bounds__(256) void k_resid_b(const float* x, const u16* y, const float* m,
                                                 int gate_off, void* o, const int* flag){
  bool f32 = flag[0] != 0;
  size_t i4 = ((size_t)blockIdx.x*256 + threadIdx.x)*4;
  int d = (int)(i4 & (D_-1));
  int b = (int)(i4 >> 21);
  float xv[4], yv[4];
  ld4(x+i4, xv); ld4(y+i4, yv);
  const float* g = m + b*6144 + gate_off + d;
  float r[4];
  #pragma unroll
  for(int j=0;j<4;j++) r[j] = xv[j] + g[j]*yv[j];
  st4g(o, i4, r, f32);
}

// ---- silu(h1)*h3 in place over h1-half of fused h13 [4096][5632]
__global__ __launch_bounds__(256) void k_silu_mul(u16* h13){
  int c4 = (blockIdx.x*256 + threadIdx.x)*4;
  if(c4 >= HID_) return;
  u16* p = h13 + (size_t)blockIdx.y*5632 + c4;
  float a[4], c[4];
  ld4(p, a); ld4(p + HID_, c);
  float r[4];
  #pragma unroll
  for(int j=0;j<4;j++){ float sv = a[j]/(1.f+__expf(-a[j])); r[j] = sv*c[j]; }
  st4(p, r);
}

extern "C" void kernel_launch(void* const* d_in, const int* in_sizes, int n_in,
                              void* d_out, int out_size, void* d_ws, size_t ws_size,
                              hipStream_t stream){
  const void* x   = d_in[0];
  const void* ada = d_in[1];
  const void* fc  = d_in[2];
  const void* fs  = d_in[3];
  const void* wq  = d_in[4];
  const void* wk  = d_in[5];
  const void* wv  = d_in[6];
  const void* wo  = d_in[7];
  const void* qnw = d_in[8];
  const void* qnb = d_in[9];
  const void* knw = d_in[10];
  const void* knb = d_in[11];
  const void* anw = d_in[12];
  const void* fnw = d_in[13];
  const void* aw  = d_in[14];
  const void* ab  = d_in[15];
  const void* w1  = d_in[16];
  const void* w2  = d_in[17];
  const void* w3  = d_in[18];
  char* ws = (char*)d_ws;
  const size_t MB = 1u<<20;

  int*   flag = (int*)ws;
  float* m    = (float*)(ws + 4096);
  u16*  hbuf  = (u16*)(ws + 1*MB);     // h -> attn-out -> h2 (8MB)
  u16*  xqkv  = (u16*)(ws + 9*MB);     // [4096][3072] (24MB); dead after attn
  float* x2   = (float*)(ws + 9*MB);   // fp32 residual (16MB), aliases xqkv
  u16*  proj  = (u16*)(ws + 25*MB);    // proj/ffn (8MB), aliases xqkv tail
  u16*  wreg  = (u16*)(ws + 33*MB);    // 12MB: wqkvT -> vt -> wtoT -> wt13T -> w2T
  u16*  h13   = (u16*)(ws + 45*MB);    // [4096][5632] (44MB) -> ends 89MB
  u16*  vt    = wreg;

  dim3 blk(256);

  k_probe_zero<<<dim3(48), blk, 0, stream>>>((const u16*)fc, flag, m);
  k_adaln<<<dim3(24,8), blk, 0, stream>>>(ada, aw, ab, m, flag);
  k_rms_mod<<<dim3(B_*S_), blk, 0, stream>>>(x, anw, m, hbuf, 0, 1024, flag);

  // fused QKV
  k_wt3<<<dim3(16,16,3), blk, 0, stream>>>(wq, wk, wv, wreg, 1024, 1024, flag);
  k_gemm_mfma<128><<<dim3(24,32), blk, 0, stream>>>(hbuf, 1024, wreg, 1024, xqkv, 4096, 3072, 1024);

  k_ln_rope2<<<dim3(B_*S_,2), blk, 0, stream>>>(xqkv, qnw, qnb, knw, knb, fc, fs, flag);
  k_vt<<<dim3(B_*H_*S_/64), blk, 0, stream>>>(xqkv + 2048, 3072, vt);
  k_attn_mfma<<<dim3(B_*H_*S_/64), blk, 0, stream>>>(xqkv, xqkv + 1024, vt, hbuf, 3072);

  k_wt3<<<dim3(16,16,1), blk, 0, stream>>>(wo, wo, wo, wreg, 1024, 1024, flag);
  k_gemm_mfma<64><<<dim3(8,64), blk, 0, stream>>>(hbuf, 1024, wreg, 1024, proj, 4096, 1024, 1024);
  k_resid_rms<<<dim3(B_*S_), blk, 0, stream>>>(x, proj, m, fnw, x2, hbuf, flag);

  // fused w1|w3
  k_wt3<<<dim3(16,44,2), blk, 0, stream>>>(w1, w3, w3, wreg, 1024, 2816, flag);
  k_gemm_mfma<128><<<dim3(44,32), blk, 0, stream>>>(hbuf, 1024, wreg, 1024, h13, 4096, 5632, 1024);
  k_silu_mul<<<dim3(3,4096), blk, 0, stream>>>(h13);
  k_wt3<<<dim3(44,16,1), blk, 0, stream>>>(w2, w2, w2, wreg, 2816, 1024, flag);
  k_gemm_mfma<64><<<dim3(8,64), blk, 0, stream>>>(h13, 5632, wreg, 2816, proj, 4096, 1024, 2816);
  k_resid_b<<<dim3(4096), blk, 0, stream>>>(x2, proj, m, 5120, d_out, flag);
}

// Round 8
// 441.767 us; speedup vs baseline: 11.8891x; 1.0348x over previous
//
#include <hip/hip_runtime.h>
#include <hip/hip_bf16.h>

#define B_   2
#define S_   2048
#define D_   1024
#define H_   16
#define HD_  64
#define HID_ 2816

typedef unsigned short u16;
typedef unsigned int   u32;
typedef __attribute__((ext_vector_type(8))) short short8;
typedef __attribute__((ext_vector_type(4))) float f32x4;
typedef __attribute__((ext_vector_type(4))) u32   u32x4;

static __device__ __forceinline__ float bf2f(u16 u){ return __uint_as_float(((u32)u)<<16); }
static __device__ __forceinline__ u16 f2bf(float f){
  u32 u = __float_as_uint(f);
  u32 r = (u + 0x7FFFu + ((u>>16)&1u)) >> 16;   // round-to-nearest-even
  return (u16)r;
}
// round-half-up bf16 (2 ops) and packed pair
static __device__ __forceinline__ u16 f2bfr(float f){
  return (u16)((__float_as_uint(f) + 0x8000u) >> 16);
}
static __device__ __forceinline__ u32 pk2(float a, float b){
  return ((__float_as_uint(a) + 0x8000u) >> 16) | ((__float_as_uint(b) + 0x8000u) & 0xFFFF0000u);
}

static __device__ __forceinline__ void ld4(const u16* p, float* v){
  ushort4 t = *reinterpret_cast<const ushort4*>(p);
  v[0]=bf2f(t.x); v[1]=bf2f(t.y); v[2]=bf2f(t.z); v[3]=bf2f(t.w);
}
static __device__ __forceinline__ void ld4(const float* p, float* v){
  float4 t = *reinterpret_cast<const float4*>(p);
  v[0]=t.x; v[1]=t.y; v[2]=t.z; v[3]=t.w;
}
static __device__ __forceinline__ void st4(u16* p, const float* v){
  ushort4 t; t.x=f2bf(v[0]); t.y=f2bf(v[1]); t.z=f2bf(v[2]); t.w=f2bf(v[3]);
  *reinterpret_cast<ushort4*>(p)=t;
}

static __device__ __forceinline__ float ld1g(const void* p, size_t i, bool f32){
  return f32 ? ((const float*)p)[i] : bf2f(((const u16*)p)[i]);
}
static __device__ __forceinline__ void ld4g(const void* p, size_t i, float* v, bool f32){
  if(f32){
    float4 t = *reinterpret_cast<const float4*>((const float*)p + i);
    v[0]=t.x; v[1]=t.y; v[2]=t.z; v[3]=t.w;
  }else{
    ushort4 t = *reinterpret_cast<const ushort4*>((const u16*)p + i);
    v[0]=bf2f(t.x); v[1]=bf2f(t.y); v[2]=bf2f(t.z); v[3]=bf2f(t.w);
  }
}
static __device__ __forceinline__ void st4g(void* p, size_t i, const float* v, bool f32){
  if(f32){
    float4 t; t.x=v[0]; t.y=v[1]; t.z=v[2]; t.w=v[3];
    *reinterpret_cast<float4*>((float*)p + i) = t;
  }else{
    st4((u16*)p + i, v);
  }
}

// async global->LDS, 16B per lane
static __device__ __forceinline__ void gl2lds16(const u16* g, const u16* l){
  typedef __attribute__((address_space(3))) u16 lds_u16;
  typedef const __attribute__((address_space(1))) u16 glb_u16;
  __builtin_amdgcn_global_load_lds((glb_u16*)(uintptr_t)g,
                                   (lds_u16*)(u32)(uintptr_t)l, 16, 0, 0);
}

// ---- probe (freqs_cos[0]==1.0f -> fp32 first u16 is 0) + zero m
__global__ __launch_bounds__(256) void k_probe_zero(const u16* fc_raw, int* flag, float* m){
  int i = blockIdx.x*256 + threadIdx.x;
  if(i < 12288) m[i] = 0.f;
  if(i == 0) *flag = (fc_raw[0]==0) ? 1 : 0;
}

static __device__ __forceinline__ float blk_sum(float v, float* red){
  #pragma unroll
  for(int o=32;o;o>>=1) v += __shfl_xor(v,o,64);
  int lane = threadIdx.x & 63, w = threadIdx.x >> 6;
  if(lane==0) red[w]=v;
  __syncthreads();
  float t = red[0]+red[1]+red[2]+red[3];
  __syncthreads();
  return t;
}

// ---- adaLN: m[b][n] = silu(a[b]) . ada_w[:,n] + ada_b[n]
__global__ __launch_bounds__(256) void k_adaln(const void* a, const void* W, const void* bias,
                                               float* m, const int* flag){
  bool f32 = flag[0] != 0;
  __shared__ float sl[2][128];
  int bk = blockIdx.y;
  {
    int bb = threadIdx.x >> 7, kk = threadIdx.x & 127;
    float x = ld1g(a, bb*D_ + bk*128 + kk, f32);
    sl[bb][kk] = x/(1.f+__expf(-x));
  }
  __syncthreads();
  int n = blockIdx.x*256 + threadIdx.x;
  float p0 = 0.f, p1 = 0.f;
  for(int kk=0;kk<128;kk++){
    float w = ld1g(W, (size_t)(bk*128+kk)*6144 + n, f32);
    p0 += sl[0][kk]*w; p1 += sl[1][kk]*w;
  }
  if(bk==0){ float bv = ld1g(bias, n, f32); p0 += bv; p1 += bv; }
  atomicAdd(&m[n], p0);
  atomicAdd(&m[6144+n], p1);
}

__global__ __launch_bounds__(256) void k_rms_mod(const void* x, const void* nw, const float* m,
                                                 u16* h, int shift_off, int scale_off,
                                                 const int* flag){
  bool f32 = flag[0] != 0;
  __shared__ float red[4];
  int row = blockIdx.x; int b = row >> 11;
  int d0 = threadIdx.x*4;
  float v[4]; ld4g(x, (size_t)row*D_ + d0, v, f32);
  float ss = v[0]*v[0]+v[1]*v[1]+v[2]*v[2]+v[3]*v[3];
  float tot = blk_sum(ss, red);
  float r = rsqrtf(tot*(1.f/D_) + 1e-5f);
  const float* mb = m + b*6144;
  float wn[4]; ld4g(nw, d0, wn, f32);
  float o[4];
  #pragma unroll
  for(int j=0;j<4;j++){
    int d = d0+j;
    o[j] = v[j]*r*wn[j]*(1.f+mb[scale_off+d]) + mb[shift_off+d];
  }
  st4(h + (size_t)row*D_ + d0, o);
}

// ---- fused: x2 = x + gate_msa*proj, then h2 = rmsnorm(x2)*(1+scale_mlp)+shift_mlp
__global__ __launch_bounds__(256) void k_resid_rms(const void* x, const u16* y, const float* m,
                                                   const void* nw, float* x2, u16* h,
                                                   const int* flag){
  bool f32 = flag[0] != 0;
  __shared__ float red[4];
  int row = blockIdx.x; int b = row >> 11;
  int d0 = threadIdx.x*4;
  size_t i4 = (size_t)row*D_ + d0;
  float xv[4], yv[4];
  ld4g(x, i4, xv, f32); ld4(y+i4, yv);
  const float* mb = m + b*6144;
  float v[4];
  #pragma unroll
  for(int j=0;j<4;j++) v[j] = xv[j] + mb[2048+d0+j]*yv[j];
  float4 t; t.x=v[0]; t.y=v[1]; t.z=v[2]; t.w=v[3];
  *reinterpret_cast<float4*>(x2+i4) = t;
  float ss = v[0]*v[0]+v[1]*v[1]+v[2]*v[2]+v[3]*v[3];
  float tot = blk_sum(ss, red);
  float r = rsqrtf(tot*(1.f/D_) + 1e-5f);
  float wn[4]; ld4g(nw, d0, wn, f32);
  float o[4];
  #pragma unroll
  for(int j=0;j<4;j++)
    o[j] = v[j]*r*wn[j]*(1.f+mb[4096+d0+j]) + mb[3072+d0+j];
  st4(h + i4, o);
}

// ---- layernorm + RoPE in place over q (y=0) and k (y=1) head slices of fused QKV
__global__ __launch_bounds__(256) void k_ln_rope2(u16* t, const void* qw, const void* qb,
                                                  const void* kw, const void* kb2,
                                                  const void* fc, const void* fs, const int* flag){
  bool f32 = flag[0] != 0;
  __shared__ float red[4];
  int row = blockIdx.x; int s = row & (S_-1);
  const void* w  = blockIdx.y ? kw  : qw;
  const void* bb = blockIdx.y ? kb2 : qb;
  int d0 = threadIdx.x*4;
  u16* tp = t + (size_t)row*3072 + blockIdx.y*1024 + d0;
  float v[4]; ld4(tp, v);
  float sm = v[0]+v[1]+v[2]+v[3];
  float sq = v[0]*v[0]+v[1]*v[1]+v[2]*v[2]+v[3]*v[3];
  float tsm = blk_sum(sm, red);
  float tsq = blk_sum(sq, red);
  float mu  = tsm*(1.f/D_);
  float var = tsq*(1.f/D_) - mu*mu;
  float rs  = rsqrtf(var + 1e-5f);
  float wv[4], bv[4]; ld4g(w, d0, wv, f32); ld4g(bb, d0, bv, f32);
  float y[4];
  #pragma unroll
  for(int j=0;j<4;j++) y[j] = (v[j]-mu)*rs*wv[j] + bv[j];
  int pos = d0 & 63; int i0 = pos>>1;
  float c0 = ld1g(fc, s*32+i0,   f32), s0 = ld1g(fs, s*32+i0,   f32);
  float c1 = ld1g(fc, s*32+i0+1, f32), s1 = ld1g(fs, s*32+i0+1, f32);
  float o[4];
  o[0] = y[0]*c0 - y[1]*s0;
  o[1] = y[0]*s0 + y[1]*c0;
  o[2] = y[2]*c1 - y[3]*s1;
  o[3] = y[2]*s1 + y[3]*c1;
  st4(tp, o);
}

// ---- weight transpose+cast, multi-source: z selects W0/W1/W2; dst offset z*Kd*Nd
__global__ __launch_bounds__(256) void k_wt3(const void* W0, const void* W1, const void* W2,
                                             u16* WT, int Kd, int Nd, const int* flag){
  bool f32 = flag[0] != 0;
  const void* W = blockIdx.z==0 ? W0 : (blockIdx.z==1 ? W1 : W2);
  u16* dst_base = WT + (size_t)blockIdx.z * (size_t)Kd * Nd;
  __shared__ u16 L[64][72];
  int tid = threadIdx.x;
  int k0 = blockIdx.x*64, n0 = blockIdx.y*64;
  int r = tid>>2, c0 = (tid&3)*16;
  if(f32){
    const float* Wf = (const float*)W;
    #pragma unroll
    for(int j=0;j<4;j++){
      float4 t = *reinterpret_cast<const float4*>(&Wf[(size_t)(k0+r)*Nd + n0 + c0 + j*4]);
      L[r][c0+j*4+0]=f2bfr(t.x); L[r][c0+j*4+1]=f2bfr(t.y);
      L[r][c0+j*4+2]=f2bfr(t.z); L[r][c0+j*4+3]=f2bfr(t.w);
    }
  }else{
    const u16* Wh = (const u16*)W;
    *reinterpret_cast<short8*>(&L[r][c0]) =
      *reinterpret_cast<const short8*>(&Wh[(size_t)(k0+r)*Nd + n0 + c0]);
    *reinterpret_cast<short8*>(&L[r][c0+8]) =
      *reinterpret_cast<const short8*>(&Wh[(size_t)(k0+r)*Nd + n0 + c0 + 8]);
  }
  __syncthreads();
  int n = tid>>2, kk0 = (tid&3)*16;
  u16 tmp[16];
  #pragma unroll
  for(int j=0;j<16;j++) tmp[j] = L[kk0+j][n];
  u16* dst = dst_base + (size_t)(n0+n)*Kd + k0 + kk0;
  *reinterpret_cast<short8*>(dst)   = *reinterpret_cast<const short8*>(tmp);
  *reinterpret_cast<short8*>(dst+8) = *reinterpret_cast<const short8*>(tmp+8);
}

// ---- w1/w3 interleaved transpose: w1 col n -> WT row (n>>5)*64+(n&31); w3 -> +32
__global__ __launch_bounds__(256) void k_wt13(const void* W1, const void* W3,
                                              u16* WT, const int* flag){
  bool f32 = flag[0] != 0;
  const int Kd = 1024, Nd = HID_;
  const void* W = blockIdx.z ? W3 : W1;
  int radd = blockIdx.z ? 32 : 0;
  __shared__ u16 L[64][72];
  int tid = threadIdx.x;
  int k0 = blockIdx.x*64, n0 = blockIdx.y*64;
  int r = tid>>2, c0 = (tid&3)*16;
  if(f32){
    const float* Wf = (const float*)W;
    #pragma unroll
    for(int j=0;j<4;j++){
      float4 t = *reinterpret_cast<const float4*>(&Wf[(size_t)(k0+r)*Nd + n0 + c0 + j*4]);
      L[r][c0+j*4+0]=f2bfr(t.x); L[r][c0+j*4+1]=f2bfr(t.y);
      L[r][c0+j*4+2]=f2bfr(t.z); L[r][c0+j*4+3]=f2bfr(t.w);
    }
  }else{
    const u16* Wh = (const u16*)W;
    *reinterpret_cast<short8*>(&L[r][c0]) =
      *reinterpret_cast<const short8*>(&Wh[(size_t)(k0+r)*Nd + n0 + c0]);
    *reinterpret_cast<short8*>(&L[r][c0+8]) =
      *reinterpret_cast<const short8*>(&Wh[(size_t)(k0+r)*Nd + n0 + c0 + 8]);
  }
  __syncthreads();
  int n = tid>>2, kk0 = (tid&3)*16;
  u16 tmp[16];
  #pragma unroll
  for(int j=0;j<16;j++) tmp[j] = L[kk0+j][n];
  int nglob = n0 + n;
  int rw = ((nglob>>5)<<6) + (nglob&31) + radd;
  u16* dst = WT + (size_t)rw*Kd + k0 + kk0;
  *reinterpret_cast<short8*>(dst)   = *reinterpret_cast<const short8*>(tmp);
  *reinterpret_cast<short8*>(dst+8) = *reinterpret_cast<const short8*>(tmp+8);
}

// ---- MFMA GEMM, XOR-swizzled LDS. EPI: 0=plain bf16 C, 1=silu-pair -> g[.][2816],
// 2=residual -> d_out (reads x2, gate).
template<int TM, int EPI>
__global__ __launch_bounds__(256) void k_gemm_mfma(const u16* A, int lda, const u16* BT, int ldb,
                                                   u16* C, int N, int K,
                                                   const float* x2, const float* mg,
                                                   void* outp, const int* flag){
  __shared__ __align__(16) u16 As[TM*64];
  __shared__ __align__(16) u16 Bs[128*64];
  int tid = threadIdx.x, lane = tid&63, w = tid>>6;
  int col = lane&15, quad = lane>>4;
  int row0 = blockIdx.y*TM, col0 = blockIdx.x*128;
  const u16* Ab = A  + (size_t)row0*lda;
  const u16* Bb = BT + (size_t)col0*ldb;
  constexpr int MI = TM/32;
  int wm = (w>>1)*(TM/2);
  int wn = (w&1)*64;
  f32x4 acc[MI][4];
  #pragma unroll
  for(int i=0;i<MI;i++)
    #pragma unroll
    for(int j=0;j<4;j++) acc[i][j] = (f32x4){0.f,0.f,0.f,0.f};

  for(int k0=0;k0<K;k0+=64){
    __syncthreads();
    #pragma unroll
    for(int i=0;i<TM/32;i++){
      int c = i*256 + w*64 + lane;
      int r = c>>3, s = c&7, gs = s ^ (r&7);
      gl2lds16(Ab + (size_t)r*lda + k0 + gs*8, As + (size_t)c*8);
    }
    #pragma unroll
    for(int i=0;i<4;i++){
      int c = i*256 + w*64 + lane;
      int r = c>>3, s = c&7, gs = s ^ (r&7);
      gl2lds16(Bb + (size_t)r*ldb + k0 + gs*8, Bs + (size_t)c*8);
    }
    __syncthreads();
    #pragma unroll
    for(int ks=0;ks<64;ks+=32){
      short8 af[MI], bfr[4];
      #pragma unroll
      for(int mi=0;mi<MI;mi++){
        int r = wm+mi*16+col;
        int sch = ((ks>>3) + quad) ^ (col&7);
        af[mi] = *reinterpret_cast<const short8*>(&As[r*64 + sch*8]);
      }
      #pragma unroll
      for(int ni=0;ni<4;ni++){
        int r = wn+ni*16+col;
        int sch = ((ks>>3) + quad) ^ (col&7);
        bfr[ni] = *reinterpret_cast<const short8*>(&Bs[r*64 + sch*8]);
      }
      #pragma unroll
      for(int mi=0;mi<MI;mi++)
        #pragma unroll
        for(int ni=0;ni<4;ni++)
          acc[mi][ni] = __builtin_amdgcn_mfma_f32_16x16x32_bf16(af[mi], bfr[ni], acc[mi][ni], 0,0,0);
    }
  }
  if constexpr(EPI==0){
    #pragma unroll
    for(int mi=0;mi<MI;mi++)
      #pragma unroll
      for(int r=0;r<4;r++){
        size_t rowoff = (size_t)(row0+wm+mi*16+quad*4+r)*N + col0 + wn;
        #pragma unroll
        for(int ni=0;ni<4;ni++)
          C[rowoff + ni*16 + col] = f2bfr(acc[mi][ni][r]);
      }
  } else if constexpr(EPI==1){
    // acc[mi][0..1] = h1 cols, acc[mi][2..3] = matching h3 cols
    int cb = blockIdx.x*64 + (wn?32:0) + col;
    #pragma unroll
    for(int mi=0;mi<MI;mi++)
      #pragma unroll
      for(int r=0;r<4;r++){
        int row = row0+wm+mi*16+quad*4+r;
        u16* gp = C + (size_t)row*HID_ + cb;
        #pragma unroll
        for(int ni=0;ni<2;ni++){
          float a = acc[mi][ni][r], cc = acc[mi][ni+2][r];
          float sv = a * __builtin_amdgcn_rcpf(1.f + __builtin_amdgcn_exp2f(-1.4426950f*a));
          gp[ni*16] = f2bfr(sv*cc);
        }
      }
  } else {
    bool f32o = flag[0] != 0;
    #pragma unroll
    for(int mi=0;mi<MI;mi++)
      #pragma unroll
      for(int r=0;r<4;r++){
        int row = row0+wm+mi*16+quad*4+r;
        int b = row >> 11;
        #pragma unroll
        for(int ni=0;ni<4;ni++){
          int cc = col0 + wn + ni*16 + col;
          float v = x2[(size_t)row*D_ + cc] + mg[b*6144 + 5120 + cc]*acc[mi][ni][r];
          if(f32o) ((float*)outp)[(size_t)row*D_ + cc] = v;
          else     ((u16*)outp)[(size_t)row*D_ + cc]   = f2bfr(v);
        }
      }
  }
}

// ---- V transpose: vt[(b*H+h)][hd][key] <- v[(b*S+key)*vstr + h*64+hd]
__global__ __launch_bounds__(256) void k_vt(const u16* v, int vstr, u16* vt){
  __shared__ u16 L[64][72];
  int tid = threadIdx.x;
  int wg = blockIdx.x;
  int kblk = wg & 31; int bh = wg >> 5; int h = bh & 15, b = bh >> 4;
  int row = tid>>2, c0 = (tid&3)*16;
  const u16* src = v + (size_t)(b*S_ + kblk*64 + row)*vstr + h*HD_ + c0;
  *reinterpret_cast<short8*>(&L[row][c0])   = *reinterpret_cast<const short8*>(src);
  *reinterpret_cast<short8*>(&L[row][c0+8]) = *reinterpret_cast<const short8*>(src+8);
  __syncthreads();
  int hd = tid>>2, k0 = (tid&3)*16;
  u16 tmp[16];
  #pragma unroll
  for(int j=0;j<16;j++) tmp[j] = L[k0+j][hd];
  u16* dst = vt + ((size_t)bh*HD_ + hd)*S_ + kblk*64 + k0;
  *reinterpret_cast<short8*>(dst)   = *reinterpret_cast<const short8*>(tmp);
  *reinterpret_cast<short8*>(dst+8) = *reinterpret_cast<const short8*>(tmp+8);
}

// ---- MFMA flash attention v4: S^T scheme + ping-pong LDS dbuf (1 barrier/chunk),
// exp2 domain, wave-uniform rescale skip.
__global__ __launch_bounds__(256) void k_attn_mfma(const u16* q, const u16* k, const u16* vt,
                                                   u16* o, int qks){
  __shared__ __align__(16) u16 Ks[2][64*72];
  __shared__ __align__(16) u16 Vs[2][64*72];
  int tid = threadIdx.x, lane = tid & 63, wid = tid >> 6;
  int col = lane & 15, quad = lane >> 4;
  int wg = blockIdx.x;
  int qblk = wg & 31; int bh = wg >> 5; int h = bh & 15, b = bh >> 4;

  const u16* kb  = k  + (size_t)b*S_*qks + h*HD_;
  const u16* vtb = vt + (size_t)bh*HD_*S_;

  short8 qa0, qa1;   // Q pre-scaled by 0.125*log2(e) -> scores in log2 domain
  {
    const float qscale = 0.18033688f;
    const u16* qp = q + (size_t)(b*S_ + qblk*64 + wid*16 + col)*qks + h*HD_ + quad*8;
    short8 t0 = *reinterpret_cast<const short8*>(qp);
    short8 t1 = *reinterpret_cast<const short8*>(qp + 32);
    #pragma unroll
    for(int j=0;j<8;j++){
      qa0[j] = (short)f2bf(bf2f((u16)t0[j])*qscale);
      qa1[j] = (short)f2bf(bf2f((u16)t1[j])*qscale);
    }
  }
  float m_i = -1e30f, l_i = 0.f;
  f32x4 acc[4];
  #pragma unroll
  for(int t=0;t<4;t++) acc[t] = (f32x4){0.f,0.f,0.f,0.f};

  // hoisted staging addresses (2 chunks of 256 lanes)
  int l0 = tid>>3,        kc0 = (tid&7)*8;
  int l1 = (256+tid)>>3,  kc1 = ((256+tid)&7)*8;
  int kl0 = 32*(l0>>5) + 8*((l0>>2)&3) + 4*((l0>>4)&1) + (l0&3);
  int kl1 = 32*(l1>>5) + 8*((l1>>2)&3) + 4*((l1>>4)&1) + (l1&3);
  const u16* kp0 = kb + (size_t)kl0*qks + kc0;
  const u16* kp1 = kb + (size_t)kl1*qks + kc1;
  const u16* vp0 = vtb + (size_t)l0*S_ + kc0;
  const u16* vp1 = vtb + (size_t)l1*S_ + kc1;
  int ko0 = l0*72 + kc0, ko1 = l1*72 + kc1;

  // prologue: stage chunk 0 into buf 0
  {
    *reinterpret_cast<short8*>(&Ks[0][ko0]) = *reinterpret_cast<const short8*>(kp0);
    *reinterpret_cast<short8*>(&Ks[0][ko1]) = *reinterpret_cast<const short8*>(kp1);
    *reinterpret_cast<short8*>(&Vs[0][ko0]) = *reinterpret_cast<const short8*>(vp0);
    *reinterpret_cast<short8*>(&Vs[0][ko1]) = *reinterpret_cast<const short8*>(vp1);
  }

  for(int i=0;i<32;i++){
    __syncthreads();
    const u16* Kc = Ks[i&1];
    const u16* Vc = Vs[i&1];
    short8 nk0, nk1, nv0, nv1;
    bool more = (i < 31);
    if(more){
      size_t t0n = (size_t)(i+1)*64;
      nk0 = *reinterpret_cast<const short8*>(kp0 + t0n*qks);
      nk1 = *reinterpret_cast<const short8*>(kp1 + t0n*qks);
      nv0 = *reinterpret_cast<const short8*>(vp0 + t0n);
      nv1 = *reinterpret_cast<const short8*>(vp1 + t0n);
    }

    f32x4 st[4];
    #pragma unroll
    for(int mt=0;mt<4;mt++){
      st[mt] = (f32x4){0.f,0.f,0.f,0.f};
      short8 ka0 = *reinterpret_cast<const short8*>(&Kc[(mt*16+col)*72 + quad*8]);
      short8 ka1 = *reinterpret_cast<const short8*>(&Kc[(mt*16+col)*72 + 32 + quad*8]);
      st[mt] = __builtin_amdgcn_mfma_f32_16x16x32_bf16(ka0, qa0, st[mt], 0,0,0);
      st[mt] = __builtin_amdgcn_mfma_f32_16x16x32_bf16(ka1, qa1, st[mt], 0,0,0);
    }
    float cm = st[0][0];
    #pragma unroll
    for(int mt=0;mt<4;mt++)
      #pragma unroll
      for(int r=0;r<4;r++) cm = fmaxf(cm, st[mt][r]);
    cm = fmaxf(cm, __shfl_xor(cm,16,64));
    cm = fmaxf(cm, __shfl_xor(cm,32,64));
    if(__any(cm > m_i)){
      float mn = fmaxf(m_i, cm);
      float al = __builtin_amdgcn_exp2f(m_i - mn);
      m_i = mn;
      l_i *= al;
      #pragma unroll
      for(int t=0;t<4;t++) acc[t] *= al;
    }
    float pe[4][4];
    #pragma unroll
    for(int mt=0;mt<4;mt++)
      #pragma unroll
      for(int r=0;r<4;r++) pe[mt][r] = __builtin_amdgcn_exp2f(st[mt][r]-m_i);
    // PV first (l-sum not needed by it)
    #pragma unroll
    for(int w=0;w<2;w++){
      u32x4 pw;
      pw[0] = pk2(pe[2*w][0],   pe[2*w][1]);
      pw[1] = pk2(pe[2*w][2],   pe[2*w][3]);
      pw[2] = pk2(pe[2*w+1][0], pe[2*w+1][1]);
      pw[3] = pk2(pe[2*w+1][2], pe[2*w+1][3]);
      short8 pb = *reinterpret_cast<short8*>(&pw);
      #pragma unroll
      for(int ht=0;ht<4;ht++){
        short8 vf = *reinterpret_cast<const short8*>(&Vc[(ht*16+col)*72 + w*32 + quad*8]);
        acc[ht] = __builtin_amdgcn_mfma_f32_16x16x32_bf16(vf, pb, acc[ht], 0,0,0);
      }
    }
    float ps = 0.f;
    #pragma unroll
    for(int mt=0;mt<4;mt++)
      #pragma unroll
      for(int r=0;r<4;r++) ps += pe[mt][r];
    ps += __shfl_xor(ps,16,64);
    ps += __shfl_xor(ps,32,64);
    l_i += ps;

    if(more){
      u16* Kn = (u16*)Ks[(i+1)&1];
      u16* Vn = (u16*)Vs[(i+1)&1];
      *reinterpret_cast<short8*>(&Kn[ko0]) = nk0;
      *reinterpret_cast<short8*>(&Kn[ko1]) = nk1;
      *reinterpret_cast<short8*>(&Vn[ko0]) = nv0;
      *reinterpret_cast<short8*>(&Vn[ko1]) = nv1;
    }
  }
  float inv = __builtin_amdgcn_rcpf(l_i);
  u16* ob = o + (size_t)(b*S_ + qblk*64 + wid*16 + col)*D_ + h*HD_;
  #pragma unroll
  for(int ht=0;ht<4;ht++){
    uint2 t;
    t.x = pk2(acc[ht][0]*inv, acc[ht][1]*inv);
    t.y = pk2(acc[ht][2]*inv, acc[ht][3]*inv);
    *reinterpret_cast<uint2*>(ob + ht*16 + quad*4) = t;
  }
}

extern "C" void kernel_launch(void* const* d_in, const int* in_sizes, int n_in,
                              void* d_out, int out_size, void* d_ws, size_t ws_size,
                              hipStream_t stream){
  const void* x   = d_in[0];
  const void* ada = d_in[1];
  const void* fc  = d_in[2];
  const void* fs  = d_in[3];
  const void* wq  = d_in[4];
  const void* wk  = d_in[5];
  const void* wv  = d_in[6];
  const void* wo  = d_in[7];
  const void* qnw = d_in[8];
  const void* qnb = d_in[9];
  const void* knw = d_in[10];
  const void* knb = d_in[11];
  const void* anw = d_in[12];
  const void* fnw = d_in[13];
  const void* aw  = d_in[14];
  const void* ab  = d_in[15];
  const void* w1  = d_in[16];
  const void* w2  = d_in[17];
  const void* w3  = d_in[18];
  char* ws = (char*)d_ws;
  const size_t MB = 1u<<20;

  int*   flag = (int*)ws;
  float* m    = (float*)(ws + 4096);
  u16*  hbuf  = (u16*)(ws + 1*MB);     // h -> attn-out -> h2 (8MB)
  u16*  xqkv  = (u16*)(ws + 9*MB);     // [4096][3072] (24MB); dead after attn
  float* x2   = (float*)(ws + 9*MB);   // fp32 residual (16MB), aliases xqkv
  u16*  proj  = (u16*)(ws + 25*MB);    // proj (8MB), aliases xqkv tail
  u16*  wreg  = (u16*)(ws + 33*MB);    // 12MB: wqkvT -> vt -> wtoT -> wt13T -> w2T
  u16*  g     = (u16*)(ws + 45*MB);    // [4096][2816] (22MB) -> ends 67MB
  u16*  vt    = wreg;

  dim3 blk(256);

  k_probe_zero<<<dim3(48), blk, 0, stream>>>((const u16*)fc, flag, m);
  k_adaln<<<dim3(24,8), blk, 0, stream>>>(ada, aw, ab, m, flag);
  k_rms_mod<<<dim3(B_*S_), blk, 0, stream>>>(x, anw, m, hbuf, 0, 1024, flag);

  // fused QKV
  k_wt3<<<dim3(16,16,3), blk, 0, stream>>>(wq, wk, wv, wreg, 1024, 1024, flag);
  k_gemm_mfma<128,0><<<dim3(24,32), blk, 0, stream>>>(hbuf, 1024, wreg, 1024, xqkv,
                                                      3072, 1024, nullptr, nullptr, nullptr, flag);

  k_ln_rope2<<<dim3(B_*S_,2), blk, 0, stream>>>(xqkv, qnw, qnb, knw, knb, fc, fs, flag);
  k_vt<<<dim3(B_*H_*S_/64), blk, 0, stream>>>(xqkv + 2048, 3072, vt);
  k_attn_mfma<<<dim3(B_*H_*S_/64), blk, 0, stream>>>(xqkv, xqkv + 1024, vt, hbuf, 3072);

  k_wt3<<<dim3(16,16,1), blk, 0, stream>>>(wo, wo, wo, wreg, 1024, 1024, flag);
  k_gemm_mfma<64,0><<<dim3(8,64), blk, 0, stream>>>(hbuf, 1024, wreg, 1024, proj,
                                                    1024, 1024, nullptr, nullptr, nullptr, flag);
  k_resid_rms<<<dim3(B_*S_), blk, 0, stream>>>(x, proj, m, fnw, x2, hbuf, flag);

  // fused w1|w3 with silu epilogue -> g
  k_wt13<<<dim3(16,44,2), blk, 0, stream>>>(w1, w3, wreg, flag);
  k_gemm_mfma<128,1><<<dim3(44,32), blk, 0, stream>>>(hbuf, 1024, wreg, 1024, g,
                                                      5632, 1024, nullptr, nullptr, nullptr, flag);
  // w2 with fused residual epilogue -> d_out
  k_wt3<<<dim3(44,16,1), blk, 0, stream>>>(w2, w2, w2, wreg, 2816, 1024, flag);
  k_gemm_mfma<64,2><<<dim3(8,64), blk, 0, stream>>>(g, 2816, wreg, 2816, nullptr,
                                                    1024, 2816, x2, m, d_out, flag);
}